// Round 18
// baseline (101.234 us; speedup 1.0000x reference)
//
#include <hip/hip_runtime.h>
#include <hip/hip_bf16.h>
#include <math.h>

// ---------------------------------------------------------------------------
// MAB block. Attention: 32x32x16 MFMA, swapped QK^T (lane-local softmax),
// no max-shift (scores bounded), row-sums via ones-MFMA, KV-split x2,
// 128-thread blocks (2 waves) x 2048 for finer workgroup packing.
// K/V AND all weight matrices pre-packed into MFMA fragment order (every
// GEMM B-load lane-contiguous, 1KB/instr). k_proj outputs staged in LDS,
// 16B vector stores. Split-combine fused into k_epi (plain-C++ cvt only —
// mass inline-asm cvt in GEMM loops miscompiles: r11/r12). r14 chain-split /
// r15 setprio regressed: reverted.
// ---------------------------------------------------------------------------

typedef __attribute__((ext_vector_type(4))) float f32x4;
typedef __attribute__((ext_vector_type(16))) float f32x16;
typedef __attribute__((ext_vector_type(8))) short s16x8;
typedef __attribute__((ext_vector_type(2))) unsigned u32x2;

#define MFMA_BF16(A, B, C) __builtin_amdgcn_mfma_f32_16x16x32_bf16((A), (B), (C), 0, 0, 0)
#define MFMA32(A, B, C) __builtin_amdgcn_mfma_f32_32x32x16_bf16((A), (B), (C), 0, 0, 0)

static __device__ __forceinline__ unsigned short f2bf(float f) {
    union { float f; unsigned u; } v; v.f = f;
    unsigned u = v.u;
    unsigned r = (u + 0x7FFFu + ((u >> 16) & 1u)) >> 16;  // RNE
    return (unsigned short)r;
}

static __device__ __forceinline__ float bf2f(unsigned short b) {
    union { unsigned u; float f; } v; v.u = ((unsigned)b) << 16;
    return v.f;
}

static __device__ __forceinline__ unsigned cvtpk(float lo, float hi) {
    unsigned r;
    asm("v_cvt_pk_bf16_f32 %0, %1, %2" : "=v"(r) : "v"(lo), "v"(hi));
    return r;
}

static __device__ __forceinline__ s16x8 mk8(unsigned a, unsigned b, unsigned c, unsigned d) {
    union { unsigned u[4]; s16x8 v; } x;
    x.u[0] = a; x.u[1] = b; x.u[2] = c; x.u[3] = d;
    return x.v;
}

// ---- fp32 -> bf16 convert: K (linear) + 4 weights (FRAGMENT-PACKED) ----
// Packed W layout (256x256 row-major source W[row][col]):
//   dst[(row>>4)*4096 + (col>>5)*512 + ((col>>3)&3)*128 + (row&15)*8 + (col&7)]
__global__ __launch_bounds__(256) void k_cvt_all(
    const float* __restrict__ K,
    const float* __restrict__ Wq, const float* __restrict__ Wk,
    const float* __restrict__ Wv, const float* __restrict__ Wo,
    unsigned short* __restrict__ Kb,
    unsigned short* __restrict__ Wqf, unsigned short* __restrict__ Wkf,
    unsigned short* __restrict__ Wvf, unsigned short* __restrict__ Wof) {
    int bid = blockIdx.x, tid = threadIdx.x;
    if (bid < 2048) {
        int idx = bid * 256 + tid;
        float4 v = ((const float4*)K)[idx];
        ushort4 o;
        o.x = f2bf(v.x); o.y = f2bf(v.y); o.z = f2bf(v.z); o.w = f2bf(v.w);
        ((ushort4*)Kb)[idx] = o;
    } else {
        int w = (bid - 2048) >> 6;
        const float* src = (w == 0) ? Wq : (w == 1) ? Wk : (w == 2) ? Wv : Wo;
        unsigned short* dst = (w == 0) ? Wqf : (w == 1) ? Wkf : (w == 2) ? Wvf : Wof;
        int idx = ((bid - 2048) & 63) * 256 + tid;
        int s = idx * 4;
        int row = s >> 8, col = s & 255;
        float4 v = ((const float4*)src)[idx];
        size_t d = (size_t)(row >> 4) * 4096 + ((size_t)(col >> 5) << 9) +
                   (((col >> 3) & 3) << 7) + ((row & 15) << 3) + (col & 7);
        ushort4 o;
        o.x = f2bf(v.x); o.y = f2bf(v.y); o.z = f2bf(v.z); o.w = f2bf(v.w);
        *(ushort4*)(dst + d) = o;  // col%8 in {0,4} -> 8B-aligned, contiguous
    }
}

// ---- merged projections, LDS-staged vectorized stores ----
// bid<256: Qp from fp32 Q (inline cvt). bid<512: Kf (fragment order).
// bid>=512: Vf (fragment order). K/V fragment order per (b,h), per 32-key
// tile t: frag f in {0,1}, elem index = t*1024 + f*512 + lane*8 + e.
__global__ __launch_bounds__(128) void k_proj(
    const float* __restrict__ Qf, const unsigned short* __restrict__ Kb,
    const unsigned short* __restrict__ Wqf, const unsigned short* __restrict__ Wkf,
    const unsigned short* __restrict__ Wvf,
    const float* __restrict__ bq, const float* __restrict__ bk, const float* __restrict__ bv,
    unsigned short* __restrict__ Qp, unsigned short* __restrict__ Kf,
    unsigned short* __restrict__ Vf, float qscale) {
    __shared__ unsigned short lds[2][16][256];  // per-wave output tile
    const int wv = threadIdx.x >> 6, lid = threadIdx.x & 63;
    const int i = lid & 15, G = lid >> 4;
    const int bid = blockIdx.x;
    if (bid < 512) {
        const int which = bid >> 8;
        const unsigned short* W = which ? Wkf : Wqf;
        const float* bias = which ? bk : bq;
        const float scale = which ? 1.0f : qscale;
        const int m0 = (bid & 255) * 32 + wv * 16;
        f32x4 acc[16];
#pragma unroll
        for (int nf = 0; nf < 16; ++nf) acc[nf] = f32x4{0.f, 0.f, 0.f, 0.f};
        const unsigned short* Xrow = Kb + (size_t)(m0 + i) * 256;
        const float* Qrow = Qf + (size_t)(m0 + i) * 256;
#pragma unroll
        for (int k0 = 0; k0 < 256; k0 += 32) {
            s16x8 a;
            if (which) {
                a = *(const s16x8*)(Xrow + k0 + G * 8);
            } else {
                float4 f0 = *(const float4*)(Qrow + k0 + G * 8);
                float4 f1 = *(const float4*)(Qrow + k0 + G * 8 + 4);
                a = mk8(cvtpk(f0.x, f0.y), cvtpk(f0.z, f0.w),
                        cvtpk(f1.x, f1.y), cvtpk(f1.z, f1.w));
            }
#pragma unroll
            for (int nf = 0; nf < 16; ++nf) {
                s16x8 b = *(const s16x8*)(W + nf * 4096 + ((k0 >> 5) << 9) + lid * 8);
                acc[nf] = MFMA_BF16(a, b, acc[nf]);
            }
        }
        // stage bf16 tile (rows m0..m0+15 x cols 0..255) in LDS
#pragma unroll
        for (int nf = 0; nf < 16; ++nf) {
            int col = nf * 16 + i;
            float bvv = bias[col];
#pragma unroll
            for (int r = 0; r < 4; ++r) {
                lds[wv][G * 4 + r][col] = f2bf((acc[nf][r] + bvv) * scale);
            }
        }
        // 8 x 16B vector stores per thread (runs of 8 output cols)
#pragma unroll
        for (int it = 0; it < 8; ++it) {
            int run = it * 64 + lid;         // 0..511 = 16 rows x 32 col-groups
            int row = run >> 5, cg = run & 31;
            int col0 = cg * 8;
            s16x8 v = *(const s16x8*)&lds[wv][row][col0];
            int m = m0 + row;
            int bb = m >> 12, j = m & 4095;
            int h = col0 >> 5, dh0 = col0 & 31;
            if (which == 0) {
                *(s16x8*)(Qp + (size_t)(((bb << 3) + h) * 4096 + j) * 32 + dh0) = v;
            } else {
                size_t off = (size_t)((bb << 3) + h) * 131072 +
                             (size_t)(j >> 5) * 1024 + ((dh0 >> 4) & 1) * 512 +
                             ((j & 31) + ((dh0 >> 3) & 1) * 32) * 8;
                *(s16x8*)(Kf + off) = v;
            }
        }
    } else {
        const int tid = bid - 512;                  // [0, 1024)
        const int n0 = (tid & 127) * 64;            // 8192 rows
        const int dv0 = (tid >> 7) * 32 + wv * 16;  // 256 dv
        f32x4 acc[4];
#pragma unroll
        for (int nf = 0; nf < 4; ++nf) acc[nf] = f32x4{0.f, 0.f, 0.f, 0.f};
        const unsigned short* Wvp = Wvf + (size_t)((tid >> 7) * 2 + wv) * 4096;
#pragma unroll
        for (int k0 = 0; k0 < 256; k0 += 32) {
            s16x8 a = *(const s16x8*)(Wvp + ((k0 >> 5) << 9) + lid * 8);
#pragma unroll
            for (int nf = 0; nf < 4; ++nf) {
                s16x8 b = *(const s16x8*)(Kb + (size_t)(n0 + nf * 16 + i) * 256 + k0 + G * 8);
                acc[nf] = MFMA_BF16(a, b, acc[nf]);
            }
        }
        // stage 16dv x 64j tile in LDS
#pragma unroll
        for (int r = 0; r < 4; ++r) {
            float bvv = bv[dv0 + G * 4 + r];
#pragma unroll
            for (int nf = 0; nf < 4; ++nf) {
                lds[wv][G * 4 + r][nf * 16 + i] = f2bf(acc[nf][r] + bvv);
            }
        }
        // 2 x 16B vector stores per thread (runs of 8 j)
#pragma unroll
        for (int it = 0; it < 2; ++it) {
            int run = it * 64 + lid;         // 0..127 = 16 dv-rows x 8 j-groups
            int row = run >> 3, jg = run & 7;
            int j0l = jg * 8;
            s16x8 v = *(const s16x8*)&lds[wv][row][j0l];
            int dv = dv0 + row;
            int j = n0 + j0l;
            int bb = j >> 12, jj = j & 4095;
            int h = dv >> 5, dvl = dv & 31;
            int rem = jj & 31;
            size_t off = (size_t)((bb << 3) + h) * 131072 +
                         (size_t)(jj >> 5) * 1024 + (rem >> 4) * 512 +
                         (size_t)(dvl + ((rem >> 3) & 1) * 32) * 8;
            *(s16x8*)(Vf + off) = v;
        }
    }
}

// ---- softmax + PV body for one 32-wide KV tile (no max-shift; r8-proven) ----
static __device__ __forceinline__ void softmax_pv(
    f32x16& st, f32x16& acc, f32x16& accL,
    const s16x8 v0, const s16x8 v1, const s16x8 ones) {
#pragma unroll
    for (int r = 0; r < 16; ++r) st[r] = __builtin_amdgcn_exp2f(st[r]);
    unsigned w00 = cvtpk(st[0], st[1]),   w01 = cvtpk(st[2], st[3]);
    unsigned w10 = cvtpk(st[4], st[5]),   w11 = cvtpk(st[6], st[7]);
    unsigned w20 = cvtpk(st[8], st[9]),   w21 = cvtpk(st[10], st[11]);
    unsigned w30 = cvtpk(st[12], st[13]), w31 = cvtpk(st[14], st[15]);
    u32x2 sA0 = __builtin_amdgcn_permlane32_swap(w00, w10, false, false);
    u32x2 sB0 = __builtin_amdgcn_permlane32_swap(w01, w11, false, false);
    u32x2 sA1 = __builtin_amdgcn_permlane32_swap(w20, w30, false, false);
    u32x2 sB1 = __builtin_amdgcn_permlane32_swap(w21, w31, false, false);
    s16x8 pa0 = mk8(sA0[0], sB0[0], sA0[1], sB0[1]);  // P, j half 0
    s16x8 pa1 = mk8(sA1[0], sB1[0], sA1[1], sB1[1]);  // P, j half 1
    acc  = MFMA32(pa0, v0, acc);
    acc  = MFMA32(pa1, v1, acc);
    accL = MFMA32(pa0, ones, accL);  // row-sums ride the MFMA pipe
    accL = MFMA32(pa1, ones, accL);
}

// ---- flash attention, KV-split x2, 128-thr blocks (2 waves), grid 2048 ----
__global__ __launch_bounds__(128, 4) void k_attn(const unsigned short* __restrict__ Qp,
                                                 const unsigned short* __restrict__ Kf,
                                                 const unsigned short* __restrict__ Vf,
                                                 unsigned short* __restrict__ Ob,
                                                 float* __restrict__ Lb) {
    const int wv = threadIdx.x >> 6, l = threadIdx.x & 63;
    const int ql = l & 31, hi = l >> 5;
    int bid = blockIdx.x;
    int wg = ((bid & 7) << 8) | (bid >> 3);  // XCD swizzle, 2048 % 8 == 0, bijective
    int bh = wg >> 7;
    int rest = wg & 127;
    int qblk = rest >> 1, sp = rest & 1;
    const unsigned short* Qh = Qp + (size_t)bh * 4096 * 32;
    const int q0 = qblk * 64 + wv * 32;

    s16x8 qb0 = *(const s16x8*)(Qh + (size_t)(q0 + ql) * 32 + hi * 8);
    s16x8 qb1 = *(const s16x8*)(Qh + (size_t)(q0 + ql) * 32 + 16 + hi * 8);

    f32x16 acc, accL, Z;
#pragma unroll
    for (int r = 0; r < 16; ++r) { acc[r] = 0.f; accL[r] = 0.f; Z[r] = 0.f; }
    const s16x8 ONES = mk8(0x3F803F80u, 0x3F803F80u, 0x3F803F80u, 0x3F803F80u);

    // fragment-order bases: per tile t, frag f: base + t*1024 + f*512 + l*8
    const unsigned short* Kl = Kf + (size_t)bh * 131072 + (size_t)sp * 65536 + l * 8;
    const unsigned short* Vl = Vf + (size_t)bh * 131072 + (size_t)sp * 65536 + l * 8;
    s16x8 kA0 = *(const s16x8*)(Kl + 0),    kA1 = *(const s16x8*)(Kl + 512);
    s16x8 kB0 = *(const s16x8*)(Kl + 1024), kB1 = *(const s16x8*)(Kl + 1536);
    s16x8 vA0 = *(const s16x8*)(Vl + 0),    vA1 = *(const s16x8*)(Vl + 512);
    s16x8 vB0 = *(const s16x8*)(Vl + 1024), vB1 = *(const s16x8*)(Vl + 1536);

    f32x16 st = MFMA32(kA0, qb0, Z);  // tile 0
    st = MFMA32(kA1, qb1, st);
    f32x16 stn;

    for (int t = 0; t < 64; t += 2) {
        {   // tile t (A bufs); QK(t+1) from B bufs overlaps softmax(t)
            int t2 = (t + 2 < 64) ? t + 2 : 62;
            kA0 = *(const s16x8*)(Kl + (size_t)t2 * 1024);
            kA1 = *(const s16x8*)(Kl + (size_t)t2 * 1024 + 512);
            stn = MFMA32(kB0, qb0, Z);
            stn = MFMA32(kB1, qb1, stn);
            softmax_pv(st, acc, accL, vA0, vA1, ONES);
            vA0 = *(const s16x8*)(Vl + (size_t)t2 * 1024);
            vA1 = *(const s16x8*)(Vl + (size_t)t2 * 1024 + 512);
            st = stn;
        }
        {   // tile t+1 (B bufs)
            int t2 = (t + 3 < 64) ? t + 3 : 62;
            kB0 = *(const s16x8*)(Kl + (size_t)t2 * 1024);
            kB1 = *(const s16x8*)(Kl + (size_t)t2 * 1024 + 512);
            stn = MFMA32(kA0, qb0, Z);
            stn = MFMA32(kA1, qb1, stn);
            softmax_pv(st, acc, accL, vB0, vB1, ONES);
            vB0 = *(const s16x8*)(Vl + (size_t)t2 * 1024);
            vB1 = *(const s16x8*)(Vl + (size_t)t2 * 1024 + 512);
            st = stn;
        }
    }

    // store normalized partial + row-sums
    const int bb = bh >> 3, h = bh & 7;
    unsigned short* Obs = Ob + (size_t)sp * 8192 * 256;
#pragma unroll
    for (int r = 0; r < 16; ++r) {
        int qr = (r & 3) + 8 * (r >> 2) + 4 * hi;
        float o = acc[r] / accL[r];
        Obs[(size_t)((bb << 12) + q0 + qr) * 256 + h * 32 + ql] = f2bf(o);
        if (ql == 0) Lb[(size_t)(sp * 16 + bh) * 4096 + q0 + qr] = accL[r];
    }
}

// ---- epilogue: combine 2 KV-split partials (plain-C++ cvt) + Wo GEMM
//      (packed bf16 Wo) + LN0 + relu-res + LN1 ----
__global__ __launch_bounds__(128) void k_epi(const unsigned short* __restrict__ Ob,
                                             const float* __restrict__ Lb,
                                             const unsigned short* __restrict__ W,
                                             const float* __restrict__ bo,
                                             const float* __restrict__ g0,
                                             const float* __restrict__ be0,
                                             const float* __restrict__ g1,
                                             const float* __restrict__ be1,
                                             float* __restrict__ out) {
    const int wv = threadIdx.x >> 6, lid = threadIdx.x & 63;
    const int i = lid & 15, G = lid >> 4;
    const int m0 = blockIdx.x * 32 + wv * 16;
    const int mrow = m0 + i;
    const int bb = mrow >> 12, qq = mrow & 4095;
    // per-head combine weights for this thread's A-row (hoisted)
    float lw0[8], lw1[8];
#pragma unroll
    for (int h = 0; h < 8; ++h) {
        float l0 = Lb[(size_t)(bb * 8 + h) * 4096 + qq];
        float l1 = Lb[(size_t)(16 + bb * 8 + h) * 4096 + qq];
        float inv = 1.f / (l0 + l1);
        lw0[h] = l0 * inv;
        lw1[h] = l1 * inv;
    }
    f32x4 acc[16];
#pragma unroll
    for (int nf = 0; nf < 16; ++nf) acc[nf] = f32x4{0.f, 0.f, 0.f, 0.f};
    const unsigned short* A0 = Ob + (size_t)mrow * 256;
    const unsigned short* A1 = Ob + (size_t)8192 * 256 + (size_t)mrow * 256;
#pragma unroll
    for (int k0 = 0; k0 < 256; k0 += 32) {
        int h = k0 >> 5;
        float w0 = lw0[h], w1 = lw1[h];
        s16x8 x0 = *(const s16x8*)(A0 + k0 + G * 8);
        s16x8 x1 = *(const s16x8*)(A1 + k0 + G * 8);
        union { unsigned short us[8]; s16x8 v; } au;
#pragma unroll
        for (int e = 0; e < 8; ++e) {
            float c = bf2f((unsigned short)x0[e]) * w0 + bf2f((unsigned short)x1[e]) * w1;
            au.us[e] = f2bf(c);
        }
        s16x8 a = au.v;
#pragma unroll
        for (int nf = 0; nf < 16; ++nf) {
            s16x8 b = *(const s16x8*)(W + nf * 4096 + ((k0 >> 5) << 9) + lid * 8);
            acc[nf] = MFMA_BF16(a, b, acc[nf]);
        }
    }
    f32x4 s1 = f32x4{0.f, 0.f, 0.f, 0.f}, s2 = f32x4{0.f, 0.f, 0.f, 0.f};
#pragma unroll
    for (int nf = 0; nf < 16; ++nf) {
        float bbv = bo[nf * 16 + i];
#pragma unroll
        for (int r = 0; r < 4; ++r) {
            float x = acc[nf][r] + bbv;
            acc[nf][r] = x;
            s1[r] += x;
            s2[r] += x * x;
        }
    }
#pragma unroll
    for (int mk = 1; mk < 16; mk <<= 1) {
#pragma unroll
        for (int r = 0; r < 4; ++r) {
            s1[r] += __shfl_xor(s1[r], mk);
            s2[r] += __shfl_xor(s2[r], mk);
        }
    }
    f32x4 mu, rs;
#pragma unroll
    for (int r = 0; r < 4; ++r) {
        mu[r] = s1[r] * (1.f / 256.f);
        float var = s2[r] * (1.f / 256.f) - mu[r] * mu[r];
        rs[r] = rsqrtf(var + 1e-5f);
    }
    f32x4 t1 = f32x4{0.f, 0.f, 0.f, 0.f}, t2 = f32x4{0.f, 0.f, 0.f, 0.f};
#pragma unroll
    for (int nf = 0; nf < 16; ++nf) {
        float gv = g0[nf * 16 + i], bv = be0[nf * 16 + i];
#pragma unroll
        for (int r = 0; r < 4; ++r) {
            float y = (acc[nf][r] - mu[r]) * rs[r] * gv + bv;
            float z = y + fmaxf(y, 0.f);
            acc[nf][r] = z;
            t1[r] += z;
            t2[r] += z * z;
        }
    }
#pragma unroll
    for (int mk = 1; mk < 16; mk <<= 1) {
#pragma unroll
        for (int r = 0; r < 4; ++r) {
            t1[r] += __shfl_xor(t1[r], mk);
            t2[r] += __shfl_xor(t2[r], mk);
        }
    }
    f32x4 mu2, rs2;
#pragma unroll
    for (int r = 0; r < 4; ++r) {
        mu2[r] = t1[r] * (1.f / 256.f);
        float var = t2[r] * (1.f / 256.f) - mu2[r] * mu2[r];
        rs2[r] = rsqrtf(var + 1e-5f);
    }
#pragma unroll
    for (int nf = 0; nf < 16; ++nf) {
        int col = nf * 16 + i;
        float gv = g1[col], bv = be1[col];
#pragma unroll
        for (int r = 0; r < 4; ++r) {
            out[(size_t)(m0 + G * 4 + r) * 256 + col] = (acc[nf][r] - mu2[r]) * rs2[r] * gv + bv;
        }
    }
}

extern "C" void kernel_launch(void* const* d_in, const int* in_sizes, int n_in,
                              void* d_out, int out_size, void* d_ws, size_t ws_size,
                              hipStream_t stream) {
    const float* Q   = (const float*)d_in[0];
    const float* K   = (const float*)d_in[1];
    const float* Wq  = (const float*)d_in[2];
    const float* bq  = (const float*)d_in[3];
    const float* Wk  = (const float*)d_in[4];
    const float* bk  = (const float*)d_in[5];
    const float* Wv  = (const float*)d_in[6];
    const float* bv  = (const float*)d_in[7];
    const float* Wo  = (const float*)d_in[8];
    const float* bo  = (const float*)d_in[9];
    const float* g0  = (const float*)d_in[10];
    const float* be0 = (const float*)d_in[11];
    const float* g1  = (const float*)d_in[12];
    const float* be1 = (const float*)d_in[13];
    float* out = (float*)d_out;

    char* ws = (char*)d_ws;
    unsigned short* Wqf = (unsigned short*)(ws + (size_t)0);
    unsigned short* Wkf = (unsigned short*)(ws + ((size_t)128 << 10));
    unsigned short* Wvf = (unsigned short*)(ws + ((size_t)256 << 10));
    unsigned short* Wof = (unsigned short*)(ws + ((size_t)384 << 10));
    size_t off = (size_t)512 << 10;
    const size_t big = (size_t)8192 * 256 * 2;  // 4 MB each
    unsigned short* Kb = (unsigned short*)(ws + off); off += big;
    unsigned short* Qp = (unsigned short*)(ws + off); off += big;
    unsigned short* Kf = (unsigned short*)(ws + off); off += big;
    unsigned short* Vf = (unsigned short*)(ws + off); off += big;
    unsigned short* Oa = (unsigned short*)(ws + off); off += big;  // unused (layout kept)
    unsigned short* Ob = (unsigned short*)(ws + off); off += 2 * big;  // split partials
    float* Lb = (float*)(ws + off); off += (size_t)2 * 16 * 4096 * 4;
    (void)Oa;

    k_cvt_all<<<2304, 256, 0, stream>>>(K, Wq, Wk, Wv, Wo,
                                        Kb, Wqf, Wkf, Wvf, Wof);

    const float qscale = 1.4426950408889634f / sqrtf(32.0f);
    k_proj<<<1536, 128, 0, stream>>>(Q, Kb, Wqf, Wkf, Wvf, bq, bk, bv,
                                     Qp, Kf, Vf, qscale);

    k_attn<<<2048, 128, 0, stream>>>(Qp, Kf, Vf, Ob, Lb);

    k_epi<<<256, 128, 0, stream>>>(Ob, Lb, Wof, bo, g0, be0, g1, be1, out);
}

// Round 19
// 100.838 us; speedup vs baseline: 1.0039x; 1.0039x over previous
//
#include <hip/hip_runtime.h>
#include <hip/hip_bf16.h>
#include <math.h>

// ---------------------------------------------------------------------------
// MAB block. Attention: 32x32x16 MFMA, swapped QK^T (lane-local softmax),
// no max-shift (scores bounded), row-sums via ones-MFMA, KV-split x2,
// T15 two-live-P-tile pipeline: PV(t) uses P computed LAST iteration, so the
// QK+PV MFMA cluster issues with no VALU wait and SM(t+1) runs under the
// in-flight MFMAs. K/V AND all weights pre-packed into MFMA fragment order.
// k_proj outputs staged in LDS, 16B vector stores. Split-combine fused into
// k_epi (plain-C++ cvt only — mass inline-asm cvt in GEMM loops miscompiles,
// r11/r12). r14 chain-split / r15 setprio / r18 block-reshape: no gain.
// ---------------------------------------------------------------------------

typedef __attribute__((ext_vector_type(4))) float f32x4;
typedef __attribute__((ext_vector_type(16))) float f32x16;
typedef __attribute__((ext_vector_type(8))) short s16x8;
typedef __attribute__((ext_vector_type(2))) unsigned u32x2;

#define MFMA_BF16(A, B, C) __builtin_amdgcn_mfma_f32_16x16x32_bf16((A), (B), (C), 0, 0, 0)
#define MFMA32(A, B, C) __builtin_amdgcn_mfma_f32_32x32x16_bf16((A), (B), (C), 0, 0, 0)

static __device__ __forceinline__ unsigned short f2bf(float f) {
    union { float f; unsigned u; } v; v.f = f;
    unsigned u = v.u;
    unsigned r = (u + 0x7FFFu + ((u >> 16) & 1u)) >> 16;  // RNE
    return (unsigned short)r;
}

static __device__ __forceinline__ float bf2f(unsigned short b) {
    union { unsigned u; float f; } v; v.u = ((unsigned)b) << 16;
    return v.f;
}

static __device__ __forceinline__ unsigned cvtpk(float lo, float hi) {
    unsigned r;
    asm("v_cvt_pk_bf16_f32 %0, %1, %2" : "=v"(r) : "v"(lo), "v"(hi));
    return r;
}

static __device__ __forceinline__ s16x8 mk8(unsigned a, unsigned b, unsigned c, unsigned d) {
    union { unsigned u[4]; s16x8 v; } x;
    x.u[0] = a; x.u[1] = b; x.u[2] = c; x.u[3] = d;
    return x.v;
}

// ---- fp32 -> bf16 convert: K (linear) + 4 weights (FRAGMENT-PACKED) ----
// Packed W layout (256x256 row-major source W[row][col]):
//   dst[(row>>4)*4096 + (col>>5)*512 + ((col>>3)&3)*128 + (row&15)*8 + (col&7)]
__global__ __launch_bounds__(256) void k_cvt_all(
    const float* __restrict__ K,
    const float* __restrict__ Wq, const float* __restrict__ Wk,
    const float* __restrict__ Wv, const float* __restrict__ Wo,
    unsigned short* __restrict__ Kb,
    unsigned short* __restrict__ Wqf, unsigned short* __restrict__ Wkf,
    unsigned short* __restrict__ Wvf, unsigned short* __restrict__ Wof) {
    int bid = blockIdx.x, tid = threadIdx.x;
    if (bid < 2048) {
        int idx = bid * 256 + tid;
        float4 v = ((const float4*)K)[idx];
        ushort4 o;
        o.x = f2bf(v.x); o.y = f2bf(v.y); o.z = f2bf(v.z); o.w = f2bf(v.w);
        ((ushort4*)Kb)[idx] = o;
    } else {
        int w = (bid - 2048) >> 6;
        const float* src = (w == 0) ? Wq : (w == 1) ? Wk : (w == 2) ? Wv : Wo;
        unsigned short* dst = (w == 0) ? Wqf : (w == 1) ? Wkf : (w == 2) ? Wvf : Wof;
        int idx = ((bid - 2048) & 63) * 256 + tid;
        int s = idx * 4;
        int row = s >> 8, col = s & 255;
        float4 v = ((const float4*)src)[idx];
        size_t d = (size_t)(row >> 4) * 4096 + ((size_t)(col >> 5) << 9) +
                   (((col >> 3) & 3) << 7) + ((row & 15) << 3) + (col & 7);
        ushort4 o;
        o.x = f2bf(v.x); o.y = f2bf(v.y); o.z = f2bf(v.z); o.w = f2bf(v.w);
        *(ushort4*)(dst + d) = o;  // col%8 in {0,4} -> 8B-aligned, contiguous
    }
}

// ---- merged projections, LDS-staged vectorized stores ----
__global__ __launch_bounds__(128) void k_proj(
    const float* __restrict__ Qf, const unsigned short* __restrict__ Kb,
    const unsigned short* __restrict__ Wqf, const unsigned short* __restrict__ Wkf,
    const unsigned short* __restrict__ Wvf,
    const float* __restrict__ bq, const float* __restrict__ bk, const float* __restrict__ bv,
    unsigned short* __restrict__ Qp, unsigned short* __restrict__ Kf,
    unsigned short* __restrict__ Vf, float qscale) {
    __shared__ unsigned short lds[2][16][256];  // per-wave output tile
    const int wv = threadIdx.x >> 6, lid = threadIdx.x & 63;
    const int i = lid & 15, G = lid >> 4;
    const int bid = blockIdx.x;
    if (bid < 512) {
        const int which = bid >> 8;
        const unsigned short* W = which ? Wkf : Wqf;
        const float* bias = which ? bk : bq;
        const float scale = which ? 1.0f : qscale;
        const int m0 = (bid & 255) * 32 + wv * 16;
        f32x4 acc[16];
#pragma unroll
        for (int nf = 0; nf < 16; ++nf) acc[nf] = f32x4{0.f, 0.f, 0.f, 0.f};
        const unsigned short* Xrow = Kb + (size_t)(m0 + i) * 256;
        const float* Qrow = Qf + (size_t)(m0 + i) * 256;
#pragma unroll
        for (int k0 = 0; k0 < 256; k0 += 32) {
            s16x8 a;
            if (which) {
                a = *(const s16x8*)(Xrow + k0 + G * 8);
            } else {
                float4 f0 = *(const float4*)(Qrow + k0 + G * 8);
                float4 f1 = *(const float4*)(Qrow + k0 + G * 8 + 4);
                a = mk8(cvtpk(f0.x, f0.y), cvtpk(f0.z, f0.w),
                        cvtpk(f1.x, f1.y), cvtpk(f1.z, f1.w));
            }
#pragma unroll
            for (int nf = 0; nf < 16; ++nf) {
                s16x8 b = *(const s16x8*)(W + nf * 4096 + ((k0 >> 5) << 9) + lid * 8);
                acc[nf] = MFMA_BF16(a, b, acc[nf]);
            }
        }
        // stage bf16 tile (rows m0..m0+15 x cols 0..255) in LDS
#pragma unroll
        for (int nf = 0; nf < 16; ++nf) {
            int col = nf * 16 + i;
            float bvv = bias[col];
#pragma unroll
            for (int r = 0; r < 4; ++r) {
                lds[wv][G * 4 + r][col] = f2bf((acc[nf][r] + bvv) * scale);
            }
        }
        // 8 x 16B vector stores per thread (runs of 8 output cols)
#pragma unroll
        for (int it = 0; it < 8; ++it) {
            int run = it * 64 + lid;         // 0..511 = 16 rows x 32 col-groups
            int row = run >> 5, cg = run & 31;
            int col0 = cg * 8;
            s16x8 v = *(const s16x8*)&lds[wv][row][col0];
            int m = m0 + row;
            int bb = m >> 12, j = m & 4095;
            int h = col0 >> 5, dh0 = col0 & 31;
            if (which == 0) {
                *(s16x8*)(Qp + (size_t)(((bb << 3) + h) * 4096 + j) * 32 + dh0) = v;
            } else {
                size_t off = (size_t)((bb << 3) + h) * 131072 +
                             (size_t)(j >> 5) * 1024 + ((dh0 >> 4) & 1) * 512 +
                             ((j & 31) + ((dh0 >> 3) & 1) * 32) * 8;
                *(s16x8*)(Kf + off) = v;
            }
        }
    } else {
        const int tid = bid - 512;                  // [0, 1024)
        const int n0 = (tid & 127) * 64;            // 8192 rows
        const int dv0 = (tid >> 7) * 32 + wv * 16;  // 256 dv
        f32x4 acc[4];
#pragma unroll
        for (int nf = 0; nf < 4; ++nf) acc[nf] = f32x4{0.f, 0.f, 0.f, 0.f};
        const unsigned short* Wvp = Wvf + (size_t)((tid >> 7) * 2 + wv) * 4096;
#pragma unroll
        for (int k0 = 0; k0 < 256; k0 += 32) {
            s16x8 a = *(const s16x8*)(Wvp + ((k0 >> 5) << 9) + lid * 8);
#pragma unroll
            for (int nf = 0; nf < 4; ++nf) {
                s16x8 b = *(const s16x8*)(Kb + (size_t)(n0 + nf * 16 + i) * 256 + k0 + G * 8);
                acc[nf] = MFMA_BF16(a, b, acc[nf]);
            }
        }
        // stage 16dv x 64j tile in LDS
#pragma unroll
        for (int r = 0; r < 4; ++r) {
            float bvv = bv[dv0 + G * 4 + r];
#pragma unroll
            for (int nf = 0; nf < 4; ++nf) {
                lds[wv][G * 4 + r][nf * 16 + i] = f2bf(acc[nf][r] + bvv);
            }
        }
        // 2 x 16B vector stores per thread (runs of 8 j)
#pragma unroll
        for (int it = 0; it < 2; ++it) {
            int run = it * 64 + lid;         // 0..127 = 16 dv-rows x 8 j-groups
            int row = run >> 3, jg = run & 7;
            int j0l = jg * 8;
            s16x8 v = *(const s16x8*)&lds[wv][row][j0l];
            int dv = dv0 + row;
            int j = n0 + j0l;
            int bb = j >> 12, jj = j & 4095;
            int h = dv >> 5, dvl = dv & 31;
            int rem = jj & 31;
            size_t off = (size_t)((bb << 3) + h) * 131072 +
                         (size_t)(jj >> 5) * 1024 + (rem >> 4) * 512 +
                         (size_t)(dvl + ((rem >> 3) & 1) * 32) * 8;
            *(s16x8*)(Vf + off) = v;
        }
    }
}

// ---- softmax of one 32-wide score tile -> P A-fragments (no max-shift) ----
static __device__ __forceinline__ void sm_tile(f32x16 st, s16x8& pa0, s16x8& pa1) {
#pragma unroll
    for (int r = 0; r < 16; ++r) st[r] = __builtin_amdgcn_exp2f(st[r]);
    unsigned w00 = cvtpk(st[0], st[1]),   w01 = cvtpk(st[2], st[3]);
    unsigned w10 = cvtpk(st[4], st[5]),   w11 = cvtpk(st[6], st[7]);
    unsigned w20 = cvtpk(st[8], st[9]),   w21 = cvtpk(st[10], st[11]);
    unsigned w30 = cvtpk(st[12], st[13]), w31 = cvtpk(st[14], st[15]);
    u32x2 sA0 = __builtin_amdgcn_permlane32_swap(w00, w10, false, false);
    u32x2 sB0 = __builtin_amdgcn_permlane32_swap(w01, w11, false, false);
    u32x2 sA1 = __builtin_amdgcn_permlane32_swap(w20, w30, false, false);
    u32x2 sB1 = __builtin_amdgcn_permlane32_swap(w21, w31, false, false);
    pa0 = mk8(sA0[0], sB0[0], sA0[1], sB0[1]);  // P, j half 0
    pa1 = mk8(sA1[0], sB1[0], sA1[1], sB1[1]);  // P, j half 1
}

// ---- flash attention, KV-split x2, T15 two-live-P-tile pipeline ----
// Per iteration: {QK(t+1) + PV(t)} MFMA cluster (PV uses prev iter's P),
// then SM(t+1) VALU runs under the in-flight MFMAs.
__global__ __launch_bounds__(256, 4) void k_attn(const unsigned short* __restrict__ Qp,
                                                 const unsigned short* __restrict__ Kf,
                                                 const unsigned short* __restrict__ Vf,
                                                 unsigned short* __restrict__ Ob,
                                                 float* __restrict__ Lb) {
    const int wv = threadIdx.x >> 6, l = threadIdx.x & 63;
    const int ql = l & 31, hi = l >> 5;
    int bid = blockIdx.x;
    int wg = ((bid & 7) << 7) | (bid >> 3);  // XCD swizzle, 1024 % 8 == 0, bijective
    int bh = wg >> 6;
    int rest = wg & 63;
    int qblk = rest >> 1, sp = rest & 1;
    const unsigned short* Qh = Qp + (size_t)bh * 4096 * 32;
    const int q0 = qblk * 128 + wv * 32;

    s16x8 qb0 = *(const s16x8*)(Qh + (size_t)(q0 + ql) * 32 + hi * 8);
    s16x8 qb1 = *(const s16x8*)(Qh + (size_t)(q0 + ql) * 32 + 16 + hi * 8);

    f32x16 acc, accL, Z;
#pragma unroll
    for (int r = 0; r < 16; ++r) { acc[r] = 0.f; accL[r] = 0.f; Z[r] = 0.f; }
    const s16x8 ONES = mk8(0x3F803F80u, 0x3F803F80u, 0x3F803F80u, 0x3F803F80u);

    // fragment-order bases: per tile t, frag f: base + t*1024 + f*512 + l*8
    const unsigned short* Kl = Kf + (size_t)bh * 131072 + (size_t)sp * 65536 + l * 8;
    const unsigned short* Vl = Vf + (size_t)bh * 131072 + (size_t)sp * 65536 + l * 8;
    s16x8 kA0 = *(const s16x8*)(Kl + 0),    kA1 = *(const s16x8*)(Kl + 512);
    s16x8 kB0 = *(const s16x8*)(Kl + 1024), kB1 = *(const s16x8*)(Kl + 1536);
    s16x8 vA0 = *(const s16x8*)(Vl + 0),    vA1 = *(const s16x8*)(Vl + 512);
    s16x8 vB0 = *(const s16x8*)(Vl + 1024), vB1 = *(const s16x8*)(Vl + 1536);

    // prologue: scores + P for tile 0
    f32x16 st = MFMA32(kA0, qb0, Z);
    st = MFMA32(kA1, qb1, st);
    s16x8 paA0, paA1, paB0, paB1;
    sm_tile(st, paA0, paA1);
    f32x16 stn;

    for (int t = 0; t < 64; t += 2) {
        {   // half-iter: QK(t+1) + PV(t) cluster; SM(t+1) under MFMA shadow
            int t2 = (t + 2 < 64) ? t + 2 : 62;
            stn  = MFMA32(kB0, qb0, Z);       // QK(t+1)
            stn  = MFMA32(kB1, qb1, stn);
            acc  = MFMA32(paA0, vA0, acc);    // PV(t), P from prev SM
            acc  = MFMA32(paA1, vA1, acc);
            accL = MFMA32(paA0, ONES, accL);
            accL = MFMA32(paA1, ONES, accL);
            kA0 = *(const s16x8*)(Kl + (size_t)t2 * 1024);
            kA1 = *(const s16x8*)(Kl + (size_t)t2 * 1024 + 512);
            sm_tile(stn, paB0, paB1);         // SM(t+1)
            vA0 = *(const s16x8*)(Vl + (size_t)t2 * 1024);
            vA1 = *(const s16x8*)(Vl + (size_t)t2 * 1024 + 512);
        }
        {   // half-iter: QK(t+2) + PV(t+1); SM(t+2)
            int t2 = (t + 3 < 64) ? t + 3 : 62;
            stn  = MFMA32(kA0, qb0, Z);       // QK(t+2) (tail: recompute, unused)
            stn  = MFMA32(kA1, qb1, stn);
            acc  = MFMA32(paB0, vB0, acc);    // PV(t+1)
            acc  = MFMA32(paB1, vB1, acc);
            accL = MFMA32(paB0, ONES, accL);
            accL = MFMA32(paB1, ONES, accL);
            kB0 = *(const s16x8*)(Kl + (size_t)t2 * 1024);
            kB1 = *(const s16x8*)(Kl + (size_t)t2 * 1024 + 512);
            sm_tile(stn, paA0, paA1);         // SM(t+2) (tail: unused)
            vB0 = *(const s16x8*)(Vl + (size_t)t2 * 1024);
            vB1 = *(const s16x8*)(Vl + (size_t)t2 * 1024 + 512);
        }
    }

    // store normalized partial + row-sums
    const int bb = bh >> 3, h = bh & 7;
    unsigned short* Obs = Ob + (size_t)sp * 8192 * 256;
#pragma unroll
    for (int r = 0; r < 16; ++r) {
        int qr = (r & 3) + 8 * (r >> 2) + 4 * hi;
        float o = acc[r] / accL[r];
        Obs[(size_t)((bb << 12) + q0 + qr) * 256 + h * 32 + ql] = f2bf(o);
        if (ql == 0) Lb[(size_t)(sp * 16 + bh) * 4096 + q0 + qr] = accL[r];
    }
}

// ---- epilogue: combine 2 KV-split partials (plain-C++ cvt) + Wo GEMM
//      (packed bf16 Wo) + LN0 + relu-res + LN1 ----
__global__ __launch_bounds__(128) void k_epi(const unsigned short* __restrict__ Ob,
                                             const float* __restrict__ Lb,
                                             const unsigned short* __restrict__ W,
                                             const float* __restrict__ bo,
                                             const float* __restrict__ g0,
                                             const float* __restrict__ be0,
                                             const float* __restrict__ g1,
                                             const float* __restrict__ be1,
                                             float* __restrict__ out) {
    const int wv = threadIdx.x >> 6, lid = threadIdx.x & 63;
    const int i = lid & 15, G = lid >> 4;
    const int m0 = blockIdx.x * 32 + wv * 16;
    const int mrow = m0 + i;
    const int bb = mrow >> 12, qq = mrow & 4095;
    // per-head combine weights for this thread's A-row (hoisted)
    float lw0[8], lw1[8];
#pragma unroll
    for (int h = 0; h < 8; ++h) {
        float l0 = Lb[(size_t)(bb * 8 + h) * 4096 + qq];
        float l1 = Lb[(size_t)(16 + bb * 8 + h) * 4096 + qq];
        float inv = 1.f / (l0 + l1);
        lw0[h] = l0 * inv;
        lw1[h] = l1 * inv;
    }
    f32x4 acc[16];
#pragma unroll
    for (int nf = 0; nf < 16; ++nf) acc[nf] = f32x4{0.f, 0.f, 0.f, 0.f};
    const unsigned short* A0 = Ob + (size_t)mrow * 256;
    const unsigned short* A1 = Ob + (size_t)8192 * 256 + (size_t)mrow * 256;
#pragma unroll
    for (int k0 = 0; k0 < 256; k0 += 32) {
        int h = k0 >> 5;
        float w0 = lw0[h], w1 = lw1[h];
        s16x8 x0 = *(const s16x8*)(A0 + k0 + G * 8);
        s16x8 x1 = *(const s16x8*)(A1 + k0 + G * 8);
        union { unsigned short us[8]; s16x8 v; } au;
#pragma unroll
        for (int e = 0; e < 8; ++e) {
            float c = bf2f((unsigned short)x0[e]) * w0 + bf2f((unsigned short)x1[e]) * w1;
            au.us[e] = f2bf(c);
        }
        s16x8 a = au.v;
#pragma unroll
        for (int nf = 0; nf < 16; ++nf) {
            s16x8 b = *(const s16x8*)(W + nf * 4096 + ((k0 >> 5) << 9) + lid * 8);
            acc[nf] = MFMA_BF16(a, b, acc[nf]);
        }
    }
    f32x4 s1 = f32x4{0.f, 0.f, 0.f, 0.f}, s2 = f32x4{0.f, 0.f, 0.f, 0.f};
#pragma unroll
    for (int nf = 0; nf < 16; ++nf) {
        float bbv = bo[nf * 16 + i];
#pragma unroll
        for (int r = 0; r < 4; ++r) {
            float x = acc[nf][r] + bbv;
            acc[nf][r] = x;
            s1[r] += x;
            s2[r] += x * x;
        }
    }
#pragma unroll
    for (int mk = 1; mk < 16; mk <<= 1) {
#pragma unroll
        for (int r = 0; r < 4; ++r) {
            s1[r] += __shfl_xor(s1[r], mk);
            s2[r] += __shfl_xor(s2[r], mk);
        }
    }
    f32x4 mu, rs;
#pragma unroll
    for (int r = 0; r < 4; ++r) {
        mu[r] = s1[r] * (1.f / 256.f);
        float var = s2[r] * (1.f / 256.f) - mu[r] * mu[r];
        rs[r] = rsqrtf(var + 1e-5f);
    }
    f32x4 t1 = f32x4{0.f, 0.f, 0.f, 0.f}, t2 = f32x4{0.f, 0.f, 0.f, 0.f};
#pragma unroll
    for (int nf = 0; nf < 16; ++nf) {
        float gv = g0[nf * 16 + i], bv = be0[nf * 16 + i];
#pragma unroll
        for (int r = 0; r < 4; ++r) {
            float y = (acc[nf][r] - mu[r]) * rs[r] * gv + bv;
            float z = y + fmaxf(y, 0.f);
            acc[nf][r] = z;
            t1[r] += z;
            t2[r] += z * z;
        }
    }
#pragma unroll
    for (int mk = 1; mk < 16; mk <<= 1) {
#pragma unroll
        for (int r = 0; r < 4; ++r) {
            t1[r] += __shfl_xor(t1[r], mk);
            t2[r] += __shfl_xor(t2[r], mk);
        }
    }
    f32x4 mu2, rs2;
#pragma unroll
    for (int r = 0; r < 4; ++r) {
        mu2[r] = t1[r] * (1.f / 256.f);
        float var = t2[r] * (1.f / 256.f) - mu2[r] * mu2[r];
        rs2[r] = rsqrtf(var + 1e-5f);
    }
#pragma unroll
    for (int nf = 0; nf < 16; ++nf) {
        int col = nf * 16 + i;
        float gv = g1[col], bv = be1[col];
#pragma unroll
        for (int r = 0; r < 4; ++r) {
            out[(size_t)(m0 + G * 4 + r) * 256 + col] = (acc[nf][r] - mu2[r]) * rs2[r] * gv + bv;
        }
    }
}

extern "C" void kernel_launch(void* const* d_in, const int* in_sizes, int n_in,
                              void* d_out, int out_size, void* d_ws, size_t ws_size,
                              hipStream_t stream) {
    const float* Q   = (const float*)d_in[0];
    const float* K   = (const float*)d_in[1];
    const float* Wq  = (const float*)d_in[2];
    const float* bq  = (const float*)d_in[3];
    const float* Wk  = (const float*)d_in[4];
    const float* bk  = (const float*)d_in[5];
    const float* Wv  = (const float*)d_in[6];
    const float* bv  = (const float*)d_in[7];
    const float* Wo  = (const float*)d_in[8];
    const float* bo  = (const float*)d_in[9];
    const float* g0  = (const float*)d_in[10];
    const float* be0 = (const float*)d_in[11];
    const float* g1  = (const float*)d_in[12];
    const float* be1 = (const float*)d_in[13];
    float* out = (float*)d_out;

    char* ws = (char*)d_ws;
    unsigned short* Wqf = (unsigned short*)(ws + (size_t)0);
    unsigned short* Wkf = (unsigned short*)(ws + ((size_t)128 << 10));
    unsigned short* Wvf = (unsigned short*)(ws + ((size_t)256 << 10));
    unsigned short* Wof = (unsigned short*)(ws + ((size_t)384 << 10));
    size_t off = (size_t)512 << 10;
    const size_t big = (size_t)8192 * 256 * 2;  // 4 MB each
    unsigned short* Kb = (unsigned short*)(ws + off); off += big;
    unsigned short* Qp = (unsigned short*)(ws + off); off += big;
    unsigned short* Kf = (unsigned short*)(ws + off); off += big;
    unsigned short* Vf = (unsigned short*)(ws + off); off += big;
    unsigned short* Oa = (unsigned short*)(ws + off); off += big;  // unused (layout kept)
    unsigned short* Ob = (unsigned short*)(ws + off); off += 2 * big;  // split partials
    float* Lb = (float*)(ws + off); off += (size_t)2 * 16 * 4096 * 4;
    (void)Oa;

    k_cvt_all<<<2304, 256, 0, stream>>>(K, Wq, Wk, Wv, Wo,
                                        Kb, Wqf, Wkf, Wvf, Wof);

    const float qscale = 1.4426950408889634f / sqrtf(32.0f);
    k_proj<<<1536, 128, 0, stream>>>(Q, Kb, Wqf, Wkf, Wvf, bq, bk, bv,
                                     Qp, Kf, Vf, qscale);

    k_attn<<<1024, 256, 0, stream>>>(Qp, Kf, Vf, Ob, Lb);

    k_epi<<<256, 128, 0, stream>>>(Ob, Lb, Wof, bo, g0, be0, g1, be1, out);
}

// Round 20
// 99.083 us; speedup vs baseline: 1.0217x; 1.0177x over previous
//
#include <hip/hip_runtime.h>
#include <hip/hip_bf16.h>
#include <math.h>

// ---------------------------------------------------------------------------
// MAB block. Attention: 32x32x16 MFMA, swapped QK^T (lane-local softmax),
// no max-shift (scores bounded), row-sums via ones-MFMA, KV-split x2,
// T15 two-live-P-tile pipeline (PV uses prev iteration's P). K/V AND all
// weights pre-packed into MFMA fragment order. k_proj outputs staged in LDS,
// 16B vector stores. Split-combine fused into k_epi (plain-C++ cvt only).
// k_epi N-split: 2 waves per 16-row tile (128 cols each), LN stats exchanged
// via LDS -> 1024 waves (was 512 on 1024 SIMDs).
// ---------------------------------------------------------------------------

typedef __attribute__((ext_vector_type(4))) float f32x4;
typedef __attribute__((ext_vector_type(16))) float f32x16;
typedef __attribute__((ext_vector_type(8))) short s16x8;
typedef __attribute__((ext_vector_type(2))) unsigned u32x2;

#define MFMA_BF16(A, B, C) __builtin_amdgcn_mfma_f32_16x16x32_bf16((A), (B), (C), 0, 0, 0)
#define MFMA32(A, B, C) __builtin_amdgcn_mfma_f32_32x32x16_bf16((A), (B), (C), 0, 0, 0)

static __device__ __forceinline__ unsigned short f2bf(float f) {
    union { float f; unsigned u; } v; v.f = f;
    unsigned u = v.u;
    unsigned r = (u + 0x7FFFu + ((u >> 16) & 1u)) >> 16;  // RNE
    return (unsigned short)r;
}

static __device__ __forceinline__ float bf2f(unsigned short b) {
    union { unsigned u; float f; } v; v.u = ((unsigned)b) << 16;
    return v.f;
}

static __device__ __forceinline__ unsigned cvtpk(float lo, float hi) {
    unsigned r;
    asm("v_cvt_pk_bf16_f32 %0, %1, %2" : "=v"(r) : "v"(lo), "v"(hi));
    return r;
}

static __device__ __forceinline__ s16x8 mk8(unsigned a, unsigned b, unsigned c, unsigned d) {
    union { unsigned u[4]; s16x8 v; } x;
    x.u[0] = a; x.u[1] = b; x.u[2] = c; x.u[3] = d;
    return x.v;
}

// ---- fp32 -> bf16 convert: K (linear) + 4 weights (FRAGMENT-PACKED) ----
// Packed W layout (256x256 row-major source W[row][col]):
//   dst[(row>>4)*4096 + (col>>5)*512 + ((col>>3)&3)*128 + (row&15)*8 + (col&7)]
__global__ __launch_bounds__(256) void k_cvt_all(
    const float* __restrict__ K,
    const float* __restrict__ Wq, const float* __restrict__ Wk,
    const float* __restrict__ Wv, const float* __restrict__ Wo,
    unsigned short* __restrict__ Kb,
    unsigned short* __restrict__ Wqf, unsigned short* __restrict__ Wkf,
    unsigned short* __restrict__ Wvf, unsigned short* __restrict__ Wof) {
    int bid = blockIdx.x, tid = threadIdx.x;
    if (bid < 2048) {
        int idx = bid * 256 + tid;
        float4 v = ((const float4*)K)[idx];
        ushort4 o;
        o.x = f2bf(v.x); o.y = f2bf(v.y); o.z = f2bf(v.z); o.w = f2bf(v.w);
        ((ushort4*)Kb)[idx] = o;
    } else {
        int w = (bid - 2048) >> 6;
        const float* src = (w == 0) ? Wq : (w == 1) ? Wk : (w == 2) ? Wv : Wo;
        unsigned short* dst = (w == 0) ? Wqf : (w == 1) ? Wkf : (w == 2) ? Wvf : Wof;
        int idx = ((bid - 2048) & 63) * 256 + tid;
        int s = idx * 4;
        int row = s >> 8, col = s & 255;
        float4 v = ((const float4*)src)[idx];
        size_t d = (size_t)(row >> 4) * 4096 + ((size_t)(col >> 5) << 9) +
                   (((col >> 3) & 3) << 7) + ((row & 15) << 3) + (col & 7);
        ushort4 o;
        o.x = f2bf(v.x); o.y = f2bf(v.y); o.z = f2bf(v.z); o.w = f2bf(v.w);
        *(ushort4*)(dst + d) = o;  // col%8 in {0,4} -> 8B-aligned, contiguous
    }
}

// ---- merged projections, LDS-staged vectorized stores ----
__global__ __launch_bounds__(128) void k_proj(
    const float* __restrict__ Qf, const unsigned short* __restrict__ Kb,
    const unsigned short* __restrict__ Wqf, const unsigned short* __restrict__ Wkf,
    const unsigned short* __restrict__ Wvf,
    const float* __restrict__ bq, const float* __restrict__ bk, const float* __restrict__ bv,
    unsigned short* __restrict__ Qp, unsigned short* __restrict__ Kf,
    unsigned short* __restrict__ Vf, float qscale) {
    __shared__ unsigned short lds[2][16][256];  // per-wave output tile
    const int wv = threadIdx.x >> 6, lid = threadIdx.x & 63;
    const int i = lid & 15, G = lid >> 4;
    const int bid = blockIdx.x;
    if (bid < 512) {
        const int which = bid >> 8;
        const unsigned short* W = which ? Wkf : Wqf;
        const float* bias = which ? bk : bq;
        const float scale = which ? 1.0f : qscale;
        const int m0 = (bid & 255) * 32 + wv * 16;
        f32x4 acc[16];
#pragma unroll
        for (int nf = 0; nf < 16; ++nf) acc[nf] = f32x4{0.f, 0.f, 0.f, 0.f};
        const unsigned short* Xrow = Kb + (size_t)(m0 + i) * 256;
        const float* Qrow = Qf + (size_t)(m0 + i) * 256;
#pragma unroll
        for (int k0 = 0; k0 < 256; k0 += 32) {
            s16x8 a;
            if (which) {
                a = *(const s16x8*)(Xrow + k0 + G * 8);
            } else {
                float4 f0 = *(const float4*)(Qrow + k0 + G * 8);
                float4 f1 = *(const float4*)(Qrow + k0 + G * 8 + 4);
                a = mk8(cvtpk(f0.x, f0.y), cvtpk(f0.z, f0.w),
                        cvtpk(f1.x, f1.y), cvtpk(f1.z, f1.w));
            }
#pragma unroll
            for (int nf = 0; nf < 16; ++nf) {
                s16x8 b = *(const s16x8*)(W + nf * 4096 + ((k0 >> 5) << 9) + lid * 8);
                acc[nf] = MFMA_BF16(a, b, acc[nf]);
            }
        }
        // stage bf16 tile (rows m0..m0+15 x cols 0..255) in LDS
#pragma unroll
        for (int nf = 0; nf < 16; ++nf) {
            int col = nf * 16 + i;
            float bvv = bias[col];
#pragma unroll
            for (int r = 0; r < 4; ++r) {
                lds[wv][G * 4 + r][col] = f2bf((acc[nf][r] + bvv) * scale);
            }
        }
        // 8 x 16B vector stores per thread (runs of 8 output cols)
#pragma unroll
        for (int it = 0; it < 8; ++it) {
            int run = it * 64 + lid;         // 0..511 = 16 rows x 32 col-groups
            int row = run >> 5, cg = run & 31;
            int col0 = cg * 8;
            s16x8 v = *(const s16x8*)&lds[wv][row][col0];
            int m = m0 + row;
            int bb = m >> 12, j = m & 4095;
            int h = col0 >> 5, dh0 = col0 & 31;
            if (which == 0) {
                *(s16x8*)(Qp + (size_t)(((bb << 3) + h) * 4096 + j) * 32 + dh0) = v;
            } else {
                size_t off = (size_t)((bb << 3) + h) * 131072 +
                             (size_t)(j >> 5) * 1024 + ((dh0 >> 4) & 1) * 512 +
                             ((j & 31) + ((dh0 >> 3) & 1) * 32) * 8;
                *(s16x8*)(Kf + off) = v;
            }
        }
    } else {
        const int tid = bid - 512;                  // [0, 1024)
        const int n0 = (tid & 127) * 64;            // 8192 rows
        const int dv0 = (tid >> 7) * 32 + wv * 16;  // 256 dv
        f32x4 acc[4];
#pragma unroll
        for (int nf = 0; nf < 4; ++nf) acc[nf] = f32x4{0.f, 0.f, 0.f, 0.f};
        const unsigned short* Wvp = Wvf + (size_t)((tid >> 7) * 2 + wv) * 4096;
#pragma unroll
        for (int k0 = 0; k0 < 256; k0 += 32) {
            s16x8 a = *(const s16x8*)(Wvp + ((k0 >> 5) << 9) + lid * 8);
#pragma unroll
            for (int nf = 0; nf < 4; ++nf) {
                s16x8 b = *(const s16x8*)(Kb + (size_t)(n0 + nf * 16 + i) * 256 + k0 + G * 8);
                acc[nf] = MFMA_BF16(a, b, acc[nf]);
            }
        }
        // stage 16dv x 64j tile in LDS
#pragma unroll
        for (int r = 0; r < 4; ++r) {
            float bvv = bv[dv0 + G * 4 + r];
#pragma unroll
            for (int nf = 0; nf < 4; ++nf) {
                lds[wv][G * 4 + r][nf * 16 + i] = f2bf(acc[nf][r] + bvv);
            }
        }
        // 2 x 16B vector stores per thread (runs of 8 j)
#pragma unroll
        for (int it = 0; it < 2; ++it) {
            int run = it * 64 + lid;         // 0..127 = 16 dv-rows x 8 j-groups
            int row = run >> 3, jg = run & 7;
            int j0l = jg * 8;
            s16x8 v = *(const s16x8*)&lds[wv][row][j0l];
            int dv = dv0 + row;
            int j = n0 + j0l;
            int bb = j >> 12, jj = j & 4095;
            int h = dv >> 5, dvl = dv & 31;
            int rem = jj & 31;
            size_t off = (size_t)((bb << 3) + h) * 131072 +
                         (size_t)(jj >> 5) * 1024 + (rem >> 4) * 512 +
                         (size_t)(dvl + ((rem >> 3) & 1) * 32) * 8;
            *(s16x8*)(Vf + off) = v;
        }
    }
}

// ---- softmax of one 32-wide score tile -> P A-fragments (no max-shift) ----
static __device__ __forceinline__ void sm_tile(f32x16 st, s16x8& pa0, s16x8& pa1) {
#pragma unroll
    for (int r = 0; r < 16; ++r) st[r] = __builtin_amdgcn_exp2f(st[r]);
    unsigned w00 = cvtpk(st[0], st[1]),   w01 = cvtpk(st[2], st[3]);
    unsigned w10 = cvtpk(st[4], st[5]),   w11 = cvtpk(st[6], st[7]);
    unsigned w20 = cvtpk(st[8], st[9]),   w21 = cvtpk(st[10], st[11]);
    unsigned w30 = cvtpk(st[12], st[13]), w31 = cvtpk(st[14], st[15]);
    u32x2 sA0 = __builtin_amdgcn_permlane32_swap(w00, w10, false, false);
    u32x2 sB0 = __builtin_amdgcn_permlane32_swap(w01, w11, false, false);
    u32x2 sA1 = __builtin_amdgcn_permlane32_swap(w20, w30, false, false);
    u32x2 sB1 = __builtin_amdgcn_permlane32_swap(w21, w31, false, false);
    pa0 = mk8(sA0[0], sB0[0], sA0[1], sB0[1]);  // P, j half 0
    pa1 = mk8(sA1[0], sB1[0], sA1[1], sB1[1]);  // P, j half 1
}

// ---- flash attention, KV-split x2, T15 two-live-P-tile pipeline ----
__global__ __launch_bounds__(256, 4) void k_attn(const unsigned short* __restrict__ Qp,
                                                 const unsigned short* __restrict__ Kf,
                                                 const unsigned short* __restrict__ Vf,
                                                 unsigned short* __restrict__ Ob,
                                                 float* __restrict__ Lb) {
    const int wv = threadIdx.x >> 6, l = threadIdx.x & 63;
    const int ql = l & 31, hi = l >> 5;
    int bid = blockIdx.x;
    int wg = ((bid & 7) << 7) | (bid >> 3);  // XCD swizzle, 1024 % 8 == 0, bijective
    int bh = wg >> 6;
    int rest = wg & 63;
    int qblk = rest >> 1, sp = rest & 1;
    const unsigned short* Qh = Qp + (size_t)bh * 4096 * 32;
    const int q0 = qblk * 128 + wv * 32;

    s16x8 qb0 = *(const s16x8*)(Qh + (size_t)(q0 + ql) * 32 + hi * 8);
    s16x8 qb1 = *(const s16x8*)(Qh + (size_t)(q0 + ql) * 32 + 16 + hi * 8);

    f32x16 acc, accL, Z;
#pragma unroll
    for (int r = 0; r < 16; ++r) { acc[r] = 0.f; accL[r] = 0.f; Z[r] = 0.f; }
    const s16x8 ONES = mk8(0x3F803F80u, 0x3F803F80u, 0x3F803F80u, 0x3F803F80u);

    // fragment-order bases: per tile t, frag f: base + t*1024 + f*512 + l*8
    const unsigned short* Kl = Kf + (size_t)bh * 131072 + (size_t)sp * 65536 + l * 8;
    const unsigned short* Vl = Vf + (size_t)bh * 131072 + (size_t)sp * 65536 + l * 8;
    s16x8 kA0 = *(const s16x8*)(Kl + 0),    kA1 = *(const s16x8*)(Kl + 512);
    s16x8 kB0 = *(const s16x8*)(Kl + 1024), kB1 = *(const s16x8*)(Kl + 1536);
    s16x8 vA0 = *(const s16x8*)(Vl + 0),    vA1 = *(const s16x8*)(Vl + 512);
    s16x8 vB0 = *(const s16x8*)(Vl + 1024), vB1 = *(const s16x8*)(Vl + 1536);

    // prologue: scores + P for tile 0
    f32x16 st = MFMA32(kA0, qb0, Z);
    st = MFMA32(kA1, qb1, st);
    s16x8 paA0, paA1, paB0, paB1;
    sm_tile(st, paA0, paA1);
    f32x16 stn;

    for (int t = 0; t < 64; t += 2) {
        {   // half-iter: QK(t+1) + PV(t) cluster; SM(t+1) under MFMA shadow
            int t2 = (t + 2 < 64) ? t + 2 : 62;
            stn  = MFMA32(kB0, qb0, Z);       // QK(t+1)
            stn  = MFMA32(kB1, qb1, stn);
            acc  = MFMA32(paA0, vA0, acc);    // PV(t), P from prev SM
            acc  = MFMA32(paA1, vA1, acc);
            accL = MFMA32(paA0, ONES, accL);
            accL = MFMA32(paA1, ONES, accL);
            kA0 = *(const s16x8*)(Kl + (size_t)t2 * 1024);
            kA1 = *(const s16x8*)(Kl + (size_t)t2 * 1024 + 512);
            sm_tile(stn, paB0, paB1);         // SM(t+1)
            vA0 = *(const s16x8*)(Vl + (size_t)t2 * 1024);
            vA1 = *(const s16x8*)(Vl + (size_t)t2 * 1024 + 512);
        }
        {   // half-iter: QK(t+2) + PV(t+1); SM(t+2)
            int t2 = (t + 3 < 64) ? t + 3 : 62;
            stn  = MFMA32(kA0, qb0, Z);       // QK(t+2) (tail: recompute, unused)
            stn  = MFMA32(kA1, qb1, stn);
            acc  = MFMA32(paB0, vB0, acc);    // PV(t+1)
            acc  = MFMA32(paB1, vB1, acc);
            accL = MFMA32(paB0, ONES, accL);
            accL = MFMA32(paB1, ONES, accL);
            kB0 = *(const s16x8*)(Kl + (size_t)t2 * 1024);
            kB1 = *(const s16x8*)(Kl + (size_t)t2 * 1024 + 512);
            sm_tile(stn, paA0, paA1);         // SM(t+2) (tail: unused)
            vB0 = *(const s16x8*)(Vl + (size_t)t2 * 1024);
            vB1 = *(const s16x8*)(Vl + (size_t)t2 * 1024 + 512);
        }
    }

    // store normalized partial + row-sums
    const int bb = bh >> 3, h = bh & 7;
    unsigned short* Obs = Ob + (size_t)sp * 8192 * 256;
#pragma unroll
    for (int r = 0; r < 16; ++r) {
        int qr = (r & 3) + 8 * (r >> 2) + 4 * hi;
        float o = acc[r] / accL[r];
        Obs[(size_t)((bb << 12) + q0 + qr) * 256 + h * 32 + ql] = f2bf(o);
        if (ql == 0) Lb[(size_t)(sp * 16 + bh) * 4096 + q0 + qr] = accL[r];
    }
}

// ---- epilogue: combine 2 KV-split partials + Wo GEMM + LN0 + relu-res + LN1
//      N-split: 2 waves per 16-row tile, each owns 128 cols; stats via LDS ----
__global__ __launch_bounds__(128) void k_epi(const unsigned short* __restrict__ Ob,
                                             const float* __restrict__ Lb,
                                             const unsigned short* __restrict__ W,
                                             const float* __restrict__ bo,
                                             const float* __restrict__ g0,
                                             const float* __restrict__ be0,
                                             const float* __restrict__ g1,
                                             const float* __restrict__ be1,
                                             float* __restrict__ out) {
    __shared__ float red[2][2][16];  // [wave][sum/sumsq][row]
    const int wv = threadIdx.x >> 6, lid = threadIdx.x & 63;
    const int i = lid & 15, G = lid >> 4;
    const int m0 = blockIdx.x * 16;
    const int mrow = m0 + i;
    const int bb = mrow >> 12, qq = mrow & 4095;
    // per-head combine weights for this thread's A-row (hoisted)
    float lw0[8], lw1[8];
#pragma unroll
    for (int h = 0; h < 8; ++h) {
        float l0 = Lb[(size_t)(bb * 8 + h) * 4096 + qq];
        float l1 = Lb[(size_t)(16 + bb * 8 + h) * 4096 + qq];
        float inv = 1.f / (l0 + l1);
        lw0[h] = l0 * inv;
        lw1[h] = l1 * inv;
    }
    f32x4 acc[8];
#pragma unroll
    for (int nf8 = 0; nf8 < 8; ++nf8) acc[nf8] = f32x4{0.f, 0.f, 0.f, 0.f};
    const unsigned short* A0 = Ob + (size_t)mrow * 256;
    const unsigned short* A1 = Ob + (size_t)8192 * 256 + (size_t)mrow * 256;
#pragma unroll
    for (int k0 = 0; k0 < 256; k0 += 32) {
        int h = k0 >> 5;
        float w0 = lw0[h], w1 = lw1[h];
        s16x8 x0 = *(const s16x8*)(A0 + k0 + G * 8);
        s16x8 x1 = *(const s16x8*)(A1 + k0 + G * 8);
        union { unsigned short us[8]; s16x8 v; } au;
#pragma unroll
        for (int e = 0; e < 8; ++e) {
            float c = bf2f((unsigned short)x0[e]) * w0 + bf2f((unsigned short)x1[e]) * w1;
            au.us[e] = f2bf(c);
        }
        s16x8 a = au.v;
#pragma unroll
        for (int nf8 = 0; nf8 < 8; ++nf8) {
            int nf = wv * 8 + nf8;
            s16x8 b = *(const s16x8*)(W + nf * 4096 + ((k0 >> 5) << 9) + lid * 8);
            acc[nf8] = MFMA_BF16(a, b, acc[nf8]);
        }
    }
    // bias + partial LN0 stats over this wave's 8 nf (128 cols)
    f32x4 s1 = f32x4{0.f, 0.f, 0.f, 0.f}, s2 = f32x4{0.f, 0.f, 0.f, 0.f};
#pragma unroll
    for (int nf8 = 0; nf8 < 8; ++nf8) {
        float bbv = bo[(wv * 8 + nf8) * 16 + i];
#pragma unroll
        for (int r = 0; r < 4; ++r) {
            float x = acc[nf8][r] + bbv;
            acc[nf8][r] = x;
            s1[r] += x;
            s2[r] += x * x;
        }
    }
#pragma unroll
    for (int mk = 1; mk < 16; mk <<= 1) {
#pragma unroll
        for (int r = 0; r < 4; ++r) {
            s1[r] += __shfl_xor(s1[r], mk);
            s2[r] += __shfl_xor(s2[r], mk);
        }
    }
    if (i == 0) {
#pragma unroll
        for (int r = 0; r < 4; ++r) {
            red[wv][0][G * 4 + r] = s1[r];
            red[wv][1][G * 4 + r] = s2[r];
        }
    }
    __syncthreads();
    f32x4 mu, rs;
#pragma unroll
    for (int r = 0; r < 4; ++r) {
        float S1 = red[0][0][G * 4 + r] + red[1][0][G * 4 + r];
        float S2 = red[0][1][G * 4 + r] + red[1][1][G * 4 + r];
        mu[r] = S1 * (1.f / 256.f);
        float var = S2 * (1.f / 256.f) - mu[r] * mu[r];
        rs[r] = rsqrtf(var + 1e-5f);
    }
    __syncthreads();  // before reusing red
    // LN0 + relu-residual, partial LN1 stats
    f32x4 t1 = f32x4{0.f, 0.f, 0.f, 0.f}, t2 = f32x4{0.f, 0.f, 0.f, 0.f};
#pragma unroll
    for (int nf8 = 0; nf8 < 8; ++nf8) {
        int col = (wv * 8 + nf8) * 16 + i;
        float gv = g0[col], bv = be0[col];
#pragma unroll
        for (int r = 0; r < 4; ++r) {
            float y = (acc[nf8][r] - mu[r]) * rs[r] * gv + bv;
            float z = y + fmaxf(y, 0.f);
            acc[nf8][r] = z;
            t1[r] += z;
            t2[r] += z * z;
        }
    }
#pragma unroll
    for (int mk = 1; mk < 16; mk <<= 1) {
#pragma unroll
        for (int r = 0; r < 4; ++r) {
            t1[r] += __shfl_xor(t1[r], mk);
            t2[r] += __shfl_xor(t2[r], mk);
        }
    }
    if (i == 0) {
#pragma unroll
        for (int r = 0; r < 4; ++r) {
            red[wv][0][G * 4 + r] = t1[r];
            red[wv][1][G * 4 + r] = t2[r];
        }
    }
    __syncthreads();
    f32x4 mu2, rs2;
#pragma unroll
    for (int r = 0; r < 4; ++r) {
        float T1 = red[0][0][G * 4 + r] + red[1][0][G * 4 + r];
        float T2 = red[0][1][G * 4 + r] + red[1][1][G * 4 + r];
        mu2[r] = T1 * (1.f / 256.f);
        float var = T2 * (1.f / 256.f) - mu2[r] * mu2[r];
        rs2[r] = rsqrtf(var + 1e-5f);
    }
#pragma unroll
    for (int nf8 = 0; nf8 < 8; ++nf8) {
        int col = (wv * 8 + nf8) * 16 + i;
        float gv = g1[col], bv = be1[col];
#pragma unroll
        for (int r = 0; r < 4; ++r) {
            out[(size_t)(m0 + G * 4 + r) * 256 + col] = (acc[nf8][r] - mu2[r]) * rs2[r] * gv + bv;
        }
    }
}

extern "C" void kernel_launch(void* const* d_in, const int* in_sizes, int n_in,
                              void* d_out, int out_size, void* d_ws, size_t ws_size,
                              hipStream_t stream) {
    const float* Q   = (const float*)d_in[0];
    const float* K   = (const float*)d_in[1];
    const float* Wq  = (const float*)d_in[2];
    const float* bq  = (const float*)d_in[3];
    const float* Wk  = (const float*)d_in[4];
    const float* bk  = (const float*)d_in[5];
    const float* Wv  = (const float*)d_in[6];
    const float* bv  = (const float*)d_in[7];
    const float* Wo  = (const float*)d_in[8];
    const float* bo  = (const float*)d_in[9];
    const float* g0  = (const float*)d_in[10];
    const float* be0 = (const float*)d_in[11];
    const float* g1  = (const float*)d_in[12];
    const float* be1 = (const float*)d_in[13];
    float* out = (float*)d_out;

    char* ws = (char*)d_ws;
    unsigned short* Wqf = (unsigned short*)(ws + (size_t)0);
    unsigned short* Wkf = (unsigned short*)(ws + ((size_t)128 << 10));
    unsigned short* Wvf = (unsigned short*)(ws + ((size_t)256 << 10));
    unsigned short* Wof = (unsigned short*)(ws + ((size_t)384 << 10));
    size_t off = (size_t)512 << 10;
    const size_t big = (size_t)8192 * 256 * 2;  // 4 MB each
    unsigned short* Kb = (unsigned short*)(ws + off); off += big;
    unsigned short* Qp = (unsigned short*)(ws + off); off += big;
    unsigned short* Kf = (unsigned short*)(ws + off); off += big;
    unsigned short* Vf = (unsigned short*)(ws + off); off += big;
    unsigned short* Oa = (unsigned short*)(ws + off); off += big;  // unused (layout kept)
    unsigned short* Ob = (unsigned short*)(ws + off); off += 2 * big;  // split partials
    float* Lb = (float*)(ws + off); off += (size_t)2 * 16 * 4096 * 4;
    (void)Oa;

    k_cvt_all<<<2304, 256, 0, stream>>>(K, Wq, Wk, Wv, Wo,
                                        Kb, Wqf, Wkf, Wvf, Wof);

    const float qscale = 1.4426950408889634f / sqrtf(32.0f);
    k_proj<<<1536, 128, 0, stream>>>(Q, Kb, Wqf, Wkf, Wvf, bq, bk, bv,
                                     Qp, Kf, Vf, qscale);

    k_attn<<<1024, 256, 0, stream>>>(Qp, Kf, Vf, Ob, Lb);

    k_epi<<<512, 128, 0, stream>>>(Ob, Lb, Wof, bo, g0, be0, g1, be1, out);
}

// Round 21
// 92.488 us; speedup vs baseline: 1.0946x; 1.0713x over previous
//
#include <hip/hip_runtime.h>
#include <hip/hip_bf16.h>
#include <math.h>

// ---------------------------------------------------------------------------
// MAB block. Attention: 32x32x16 MFMA, swapped QK^T (lane-local softmax),
// no max-shift (scores bounded), row-sums via ones-MFMA, KV-split x2,
// T15 two-live-P-tile pipeline. K (raw), K/V projections AND all weights
// pre-packed into MFMA fragment order -> every GEMM A/B load in proj/attn/epi
// is lane-contiguous (1KB/instr). k_proj outputs staged in LDS, 16B vector
// stores. Split-combine fused into k_epi (plain-C++ cvt only). k_epi N-split
// (2 waves x 128 cols, LN stats via LDS).
// ---------------------------------------------------------------------------

typedef __attribute__((ext_vector_type(4))) float f32x4;
typedef __attribute__((ext_vector_type(16))) float f32x16;
typedef __attribute__((ext_vector_type(8))) short s16x8;
typedef __attribute__((ext_vector_type(2))) unsigned u32x2;

#define MFMA_BF16(A, B, C) __builtin_amdgcn_mfma_f32_16x16x32_bf16((A), (B), (C), 0, 0, 0)
#define MFMA32(A, B, C) __builtin_amdgcn_mfma_f32_32x32x16_bf16((A), (B), (C), 0, 0, 0)

static __device__ __forceinline__ unsigned short f2bf(float f) {
    union { float f; unsigned u; } v; v.f = f;
    unsigned u = v.u;
    unsigned r = (u + 0x7FFFu + ((u >> 16) & 1u)) >> 16;  // RNE
    return (unsigned short)r;
}

static __device__ __forceinline__ float bf2f(unsigned short b) {
    union { unsigned u; float f; } v; v.u = ((unsigned)b) << 16;
    return v.f;
}

static __device__ __forceinline__ unsigned cvtpk(float lo, float hi) {
    unsigned r;
    asm("v_cvt_pk_bf16_f32 %0, %1, %2" : "=v"(r) : "v"(lo), "v"(hi));
    return r;
}

static __device__ __forceinline__ s16x8 mk8(unsigned a, unsigned b, unsigned c, unsigned d) {
    union { unsigned u[4]; s16x8 v; } x;
    x.u[0] = a; x.u[1] = b; x.u[2] = c; x.u[3] = d;
    return x.v;
}

// fragment-pack destination offset for a [rows][256] row-major source:
//   (row>>4)*4096 + (col>>5)*512 + ((col>>3)&3)*128 + (row&15)*8 + (col&7)
// => a wave's fragment load for 16-aligned row block RB, k-block kb is
//    base + RB*4096 + kb*512 + lane*8   (lane-contiguous 1KB)
static __device__ __forceinline__ size_t packoff(int row, int col) {
    return (size_t)(row >> 4) * 4096 + ((size_t)(col >> 5) << 9) +
           (((col >> 3) & 3) << 7) + ((row & 15) << 3) + (col & 7);
}

// ---- fp32 -> bf16 convert: K AND 4 weights, all FRAGMENT-PACKED ----
__global__ __launch_bounds__(256) void k_cvt_all(
    const float* __restrict__ K,
    const float* __restrict__ Wq, const float* __restrict__ Wk,
    const float* __restrict__ Wv, const float* __restrict__ Wo,
    unsigned short* __restrict__ Kfp,
    unsigned short* __restrict__ Wqf, unsigned short* __restrict__ Wkf,
    unsigned short* __restrict__ Wvf, unsigned short* __restrict__ Wof) {
    int bid = blockIdx.x, tid = threadIdx.x;
    const float* src;
    unsigned short* dst;
    int idx;
    if (bid < 2048) {
        src = K; dst = Kfp; idx = bid * 256 + tid;
    } else {
        int w = (bid - 2048) >> 6;
        src = (w == 0) ? Wq : (w == 1) ? Wk : (w == 2) ? Wv : Wo;
        dst = (w == 0) ? Wqf : (w == 1) ? Wkf : (w == 2) ? Wvf : Wof;
        idx = ((bid - 2048) & 63) * 256 + tid;
    }
    int s = idx * 4;
    int row = s >> 8, col = s & 255;
    float4 v = ((const float4*)src)[idx];
    size_t d = packoff(row, col);
    ushort4 o;
    o.x = f2bf(v.x); o.y = f2bf(v.y); o.z = f2bf(v.z); o.w = f2bf(v.w);
    *(ushort4*)(dst + d) = o;  // col%8 in {0,4} -> 8B-aligned, contiguous
}

// ---- merged projections, fully-packed operand loads, LDS-staged stores ----
// bid<256: Qp from fp32 Q (inline cvt). bid<512: Kf (attn fragment order).
// bid>=512: Vf. K raw reads come from packed Kfp (1KB lane-contiguous).
__global__ __launch_bounds__(128) void k_proj(
    const float* __restrict__ Qf, const unsigned short* __restrict__ Kfp,
    const unsigned short* __restrict__ Wqf, const unsigned short* __restrict__ Wkf,
    const unsigned short* __restrict__ Wvf,
    const float* __restrict__ bq, const float* __restrict__ bk, const float* __restrict__ bv,
    unsigned short* __restrict__ Qp, unsigned short* __restrict__ Kf,
    unsigned short* __restrict__ Vf, float qscale) {
    __shared__ unsigned short lds[2][16][256];  // per-wave output tile
    const int wv = threadIdx.x >> 6, lid = threadIdx.x & 63;
    const int i = lid & 15, G = lid >> 4;
    const int bid = blockIdx.x;
    if (bid < 512) {
        const int which = bid >> 8;
        const unsigned short* W = which ? Wkf : Wqf;
        const float* bias = which ? bk : bq;
        const float scale = which ? 1.0f : qscale;
        const int m0 = (bid & 255) * 32 + wv * 16;
        f32x4 acc[16];
#pragma unroll
        for (int nf = 0; nf < 16; ++nf) acc[nf] = f32x4{0.f, 0.f, 0.f, 0.f};
        const float* Qrow = Qf + (size_t)(m0 + i) * 256;
        const unsigned short* Krb = Kfp + (size_t)(m0 >> 4) * 4096 + lid * 8;
#pragma unroll
        for (int k0 = 0; k0 < 256; k0 += 32) {
            s16x8 a;
            if (which) {
                a = *(const s16x8*)(Krb + ((k0 >> 5) << 9));
            } else {
                float4 f0 = *(const float4*)(Qrow + k0 + G * 8);
                float4 f1 = *(const float4*)(Qrow + k0 + G * 8 + 4);
                a = mk8(cvtpk(f0.x, f0.y), cvtpk(f0.z, f0.w),
                        cvtpk(f1.x, f1.y), cvtpk(f1.z, f1.w));
            }
#pragma unroll
            for (int nf = 0; nf < 16; ++nf) {
                s16x8 b = *(const s16x8*)(W + nf * 4096 + ((k0 >> 5) << 9) + lid * 8);
                acc[nf] = MFMA_BF16(a, b, acc[nf]);
            }
        }
        // stage bf16 tile (rows m0..m0+15 x cols 0..255) in LDS
#pragma unroll
        for (int nf = 0; nf < 16; ++nf) {
            int col = nf * 16 + i;
            float bvv = bias[col];
#pragma unroll
            for (int r = 0; r < 4; ++r) {
                lds[wv][G * 4 + r][col] = f2bf((acc[nf][r] + bvv) * scale);
            }
        }
        // 8 x 16B vector stores per thread (runs of 8 output cols)
#pragma unroll
        for (int it = 0; it < 8; ++it) {
            int run = it * 64 + lid;         // 0..511 = 16 rows x 32 col-groups
            int row = run >> 5, cg = run & 31;
            int col0 = cg * 8;
            s16x8 v = *(const s16x8*)&lds[wv][row][col0];
            int m = m0 + row;
            int bb = m >> 12, j = m & 4095;
            int h = col0 >> 5, dh0 = col0 & 31;
            if (which == 0) {
                *(s16x8*)(Qp + (size_t)(((bb << 3) + h) * 4096 + j) * 32 + dh0) = v;
            } else {
                size_t off = (size_t)((bb << 3) + h) * 131072 +
                             (size_t)(j >> 5) * 1024 + ((dh0 >> 4) & 1) * 512 +
                             ((j & 31) + ((dh0 >> 3) & 1) * 32) * 8;
                *(s16x8*)(Kf + off) = v;
            }
        }
    } else {
        const int tid = bid - 512;                  // [0, 1024)
        const int n0 = (tid & 127) * 64;            // 8192 rows
        const int dv0 = (tid >> 7) * 32 + wv * 16;  // 256 dv
        f32x4 acc[4];
#pragma unroll
        for (int nf = 0; nf < 4; ++nf) acc[nf] = f32x4{0.f, 0.f, 0.f, 0.f};
        const unsigned short* Wvp = Wvf + (size_t)((tid >> 7) * 2 + wv) * 4096;
        const unsigned short* Krb = Kfp + (size_t)(n0 >> 4) * 4096 + lid * 8;
#pragma unroll
        for (int k0 = 0; k0 < 256; k0 += 32) {
            s16x8 a = *(const s16x8*)(Wvp + ((k0 >> 5) << 9) + lid * 8);
#pragma unroll
            for (int nf = 0; nf < 4; ++nf) {
                s16x8 b = *(const s16x8*)(Krb + (size_t)nf * 4096 + ((k0 >> 5) << 9));
                acc[nf] = MFMA_BF16(a, b, acc[nf]);
            }
        }
        // stage 16dv x 64j tile in LDS
#pragma unroll
        for (int r = 0; r < 4; ++r) {
            float bvv = bv[dv0 + G * 4 + r];
#pragma unroll
            for (int nf = 0; nf < 4; ++nf) {
                lds[wv][G * 4 + r][nf * 16 + i] = f2bf(acc[nf][r] + bvv);
            }
        }
        // 2 x 16B vector stores per thread (runs of 8 j)
#pragma unroll
        for (int it = 0; it < 2; ++it) {
            int run = it * 64 + lid;         // 0..127 = 16 dv-rows x 8 j-groups
            int row = run >> 3, jg = run & 7;
            int j0l = jg * 8;
            s16x8 v = *(const s16x8*)&lds[wv][row][j0l];
            int dv = dv0 + row;
            int j = n0 + j0l;
            int bb = j >> 12, jj = j & 4095;
            int h = dv >> 5, dvl = dv & 31;
            int rem = jj & 31;
            size_t off = (size_t)((bb << 3) + h) * 131072 +
                         (size_t)(jj >> 5) * 1024 + (rem >> 4) * 512 +
                         (size_t)(dvl + ((rem >> 3) & 1) * 32) * 8;
            *(s16x8*)(Vf + off) = v;
        }
    }
}

// ---- softmax of one 32-wide score tile -> P A-fragments (no max-shift) ----
static __device__ __forceinline__ void sm_tile(f32x16 st, s16x8& pa0, s16x8& pa1) {
#pragma unroll
    for (int r = 0; r < 16; ++r) st[r] = __builtin_amdgcn_exp2f(st[r]);
    unsigned w00 = cvtpk(st[0], st[1]),   w01 = cvtpk(st[2], st[3]);
    unsigned w10 = cvtpk(st[4], st[5]),   w11 = cvtpk(st[6], st[7]);
    unsigned w20 = cvtpk(st[8], st[9]),   w21 = cvtpk(st[10], st[11]);
    unsigned w30 = cvtpk(st[12], st[13]), w31 = cvtpk(st[14], st[15]);
    u32x2 sA0 = __builtin_amdgcn_permlane32_swap(w00, w10, false, false);
    u32x2 sB0 = __builtin_amdgcn_permlane32_swap(w01, w11, false, false);
    u32x2 sA1 = __builtin_amdgcn_permlane32_swap(w20, w30, false, false);
    u32x2 sB1 = __builtin_amdgcn_permlane32_swap(w21, w31, false, false);
    pa0 = mk8(sA0[0], sB0[0], sA0[1], sB0[1]);  // P, j half 0
    pa1 = mk8(sA1[0], sB1[0], sA1[1], sB1[1]);  // P, j half 1
}

// ---- flash attention, KV-split x2, T15 two-live-P-tile pipeline ----
__global__ __launch_bounds__(256, 4) void k_attn(const unsigned short* __restrict__ Qp,
                                                 const unsigned short* __restrict__ Kf,
                                                 const unsigned short* __restrict__ Vf,
                                                 unsigned short* __restrict__ Ob,
                                                 float* __restrict__ Lb) {
    const int wv = threadIdx.x >> 6, l = threadIdx.x & 63;
    const int ql = l & 31, hi = l >> 5;
    int bid = blockIdx.x;
    int wg = ((bid & 7) << 7) | (bid >> 3);  // XCD swizzle, 1024 % 8 == 0, bijective
    int bh = wg >> 6;
    int rest = wg & 63;
    int qblk = rest >> 1, sp = rest & 1;
    const unsigned short* Qh = Qp + (size_t)bh * 4096 * 32;
    const int q0 = qblk * 128 + wv * 32;

    s16x8 qb0 = *(const s16x8*)(Qh + (size_t)(q0 + ql) * 32 + hi * 8);
    s16x8 qb1 = *(const s16x8*)(Qh + (size_t)(q0 + ql) * 32 + 16 + hi * 8);

    f32x16 acc, accL, Z;
#pragma unroll
    for (int r = 0; r < 16; ++r) { acc[r] = 0.f; accL[r] = 0.f; Z[r] = 0.f; }
    const s16x8 ONES = mk8(0x3F803F80u, 0x3F803F80u, 0x3F803F80u, 0x3F803F80u);

    // fragment-order bases: per tile t, frag f: base + t*1024 + f*512 + l*8
    const unsigned short* Kl = Kf + (size_t)bh * 131072 + (size_t)sp * 65536 + l * 8;
    const unsigned short* Vl = Vf + (size_t)bh * 131072 + (size_t)sp * 65536 + l * 8;
    s16x8 kA0 = *(const s16x8*)(Kl + 0),    kA1 = *(const s16x8*)(Kl + 512);
    s16x8 kB0 = *(const s16x8*)(Kl + 1024), kB1 = *(const s16x8*)(Kl + 1536);
    s16x8 vA0 = *(const s16x8*)(Vl + 0),    vA1 = *(const s16x8*)(Vl + 512);
    s16x8 vB0 = *(const s16x8*)(Vl + 1024), vB1 = *(const s16x8*)(Vl + 1536);

    // prologue: scores + P for tile 0
    f32x16 st = MFMA32(kA0, qb0, Z);
    st = MFMA32(kA1, qb1, st);
    s16x8 paA0, paA1, paB0, paB1;
    sm_tile(st, paA0, paA1);
    f32x16 stn;

    for (int t = 0; t < 64; t += 2) {
        {   // half-iter: QK(t+1) + PV(t) cluster; SM(t+1) under MFMA shadow
            int t2 = (t + 2 < 64) ? t + 2 : 62;
            stn  = MFMA32(kB0, qb0, Z);       // QK(t+1)
            stn  = MFMA32(kB1, qb1, stn);
            acc  = MFMA32(paA0, vA0, acc);    // PV(t), P from prev SM
            acc  = MFMA32(paA1, vA1, acc);
            accL = MFMA32(paA0, ONES, accL);
            accL = MFMA32(paA1, ONES, accL);
            kA0 = *(const s16x8*)(Kl + (size_t)t2 * 1024);
            kA1 = *(const s16x8*)(Kl + (size_t)t2 * 1024 + 512);
            sm_tile(stn, paB0, paB1);         // SM(t+1)
            vA0 = *(const s16x8*)(Vl + (size_t)t2 * 1024);
            vA1 = *(const s16x8*)(Vl + (size_t)t2 * 1024 + 512);
        }
        {   // half-iter: QK(t+2) + PV(t+1); SM(t+2)
            int t2 = (t + 3 < 64) ? t + 3 : 62;
            stn  = MFMA32(kA0, qb0, Z);       // QK(t+2) (tail: recompute, unused)
            stn  = MFMA32(kA1, qb1, stn);
            acc  = MFMA32(paB0, vB0, acc);    // PV(t+1)
            acc  = MFMA32(paB1, vB1, acc);
            accL = MFMA32(paB0, ONES, accL);
            accL = MFMA32(paB1, ONES, accL);
            kB0 = *(const s16x8*)(Kl + (size_t)t2 * 1024);
            kB1 = *(const s16x8*)(Kl + (size_t)t2 * 1024 + 512);
            sm_tile(stn, paA0, paA1);         // SM(t+2) (tail: unused)
            vB0 = *(const s16x8*)(Vl + (size_t)t2 * 1024);
            vB1 = *(const s16x8*)(Vl + (size_t)t2 * 1024 + 512);
        }
    }

    // store normalized partial + row-sums
    const int bb = bh >> 3, h = bh & 7;
    unsigned short* Obs = Ob + (size_t)sp * 8192 * 256;
#pragma unroll
    for (int r = 0; r < 16; ++r) {
        int qr = (r & 3) + 8 * (r >> 2) + 4 * hi;
        float o = acc[r] / accL[r];
        Obs[(size_t)((bb << 12) + q0 + qr) * 256 + h * 32 + ql] = f2bf(o);
        if (ql == 0) Lb[(size_t)(sp * 16 + bh) * 4096 + q0 + qr] = accL[r];
    }
}

// ---- epilogue: combine 2 KV-split partials + Wo GEMM + LN0 + relu-res + LN1
//      N-split: 2 waves per 16-row tile, each owns 128 cols; stats via LDS ----
__global__ __launch_bounds__(128) void k_epi(const unsigned short* __restrict__ Ob,
                                             const float* __restrict__ Lb,
                                             const unsigned short* __restrict__ W,
                                             const float* __restrict__ bo,
                                             const float* __restrict__ g0,
                                             const float* __restrict__ be0,
                                             const float* __restrict__ g1,
                                             const float* __restrict__ be1,
                                             float* __restrict__ out) {
    __shared__ float red[2][2][16];  // [wave][sum/sumsq][row]
    const int wv = threadIdx.x >> 6, lid = threadIdx.x & 63;
    const int i = lid & 15, G = lid >> 4;
    const int m0 = blockIdx.x * 16;
    const int mrow = m0 + i;
    const int bb = mrow >> 12, qq = mrow & 4095;
    // per-head combine weights for this thread's A-row (hoisted)
    float lw0[8], lw1[8];
#pragma unroll
    for (int h = 0; h < 8; ++h) {
        float l0 = Lb[(size_t)(bb * 8 + h) * 4096 + qq];
        float l1 = Lb[(size_t)(16 + bb * 8 + h) * 4096 + qq];
        float inv = 1.f / (l0 + l1);
        lw0[h] = l0 * inv;
        lw1[h] = l1 * inv;
    }
    f32x4 acc[8];
#pragma unroll
    for (int nf8 = 0; nf8 < 8; ++nf8) acc[nf8] = f32x4{0.f, 0.f, 0.f, 0.f};
    const unsigned short* A0 = Ob + (size_t)mrow * 256;
    const unsigned short* A1 = Ob + (size_t)8192 * 256 + (size_t)mrow * 256;
#pragma unroll
    for (int k0 = 0; k0 < 256; k0 += 32) {
        int h = k0 >> 5;
        float w0 = lw0[h], w1 = lw1[h];
        s16x8 x0 = *(const s16x8*)(A0 + k0 + G * 8);
        s16x8 x1 = *(const s16x8*)(A1 + k0 + G * 8);
        union { unsigned short us[8]; s16x8 v; } au;
#pragma unroll
        for (int e = 0; e < 8; ++e) {
            float c = bf2f((unsigned short)x0[e]) * w0 + bf2f((unsigned short)x1[e]) * w1;
            au.us[e] = f2bf(c);
        }
        s16x8 a = au.v;
#pragma unroll
        for (int nf8 = 0; nf8 < 8; ++nf8) {
            int nf = wv * 8 + nf8;
            s16x8 b = *(const s16x8*)(W + nf * 4096 + ((k0 >> 5) << 9) + lid * 8);
            acc[nf8] = MFMA_BF16(a, b, acc[nf8]);
        }
    }
    // bias + partial LN0 stats over this wave's 8 nf (128 cols)
    f32x4 s1 = f32x4{0.f, 0.f, 0.f, 0.f}, s2 = f32x4{0.f, 0.f, 0.f, 0.f};
#pragma unroll
    for (int nf8 = 0; nf8 < 8; ++nf8) {
        float bbv = bo[(wv * 8 + nf8) * 16 + i];
#pragma unroll
        for (int r = 0; r < 4; ++r) {
            float x = acc[nf8][r] + bbv;
            acc[nf8][r] = x;
            s1[r] += x;
            s2[r] += x * x;
        }
    }
#pragma unroll
    for (int mk = 1; mk < 16; mk <<= 1) {
#pragma unroll
        for (int r = 0; r < 4; ++r) {
            s1[r] += __shfl_xor(s1[r], mk);
            s2[r] += __shfl_xor(s2[r], mk);
        }
    }
    if (i == 0) {
#pragma unroll
        for (int r = 0; r < 4; ++r) {
            red[wv][0][G * 4 + r] = s1[r];
            red[wv][1][G * 4 + r] = s2[r];
        }
    }
    __syncthreads();
    f32x4 mu, rs;
#pragma unroll
    for (int r = 0; r < 4; ++r) {
        float S1 = red[0][0][G * 4 + r] + red[1][0][G * 4 + r];
        float S2 = red[0][1][G * 4 + r] + red[1][1][G * 4 + r];
        mu[r] = S1 * (1.f / 256.f);
        float var = S2 * (1.f / 256.f) - mu[r] * mu[r];
        rs[r] = rsqrtf(var + 1e-5f);
    }
    __syncthreads();  // before reusing red
    // LN0 + relu-residual, partial LN1 stats
    f32x4 t1 = f32x4{0.f, 0.f, 0.f, 0.f}, t2 = f32x4{0.f, 0.f, 0.f, 0.f};
#pragma unroll
    for (int nf8 = 0; nf8 < 8; ++nf8) {
        int col = (wv * 8 + nf8) * 16 + i;
        float gv = g0[col], bv = be0[col];
#pragma unroll
        for (int r = 0; r < 4; ++r) {
            float y = (acc[nf8][r] - mu[r]) * rs[r] * gv + bv;
            float z = y + fmaxf(y, 0.f);
            acc[nf8][r] = z;
            t1[r] += z;
            t2[r] += z * z;
        }
    }
#pragma unroll
    for (int mk = 1; mk < 16; mk <<= 1) {
#pragma unroll
        for (int r = 0; r < 4; ++r) {
            t1[r] += __shfl_xor(t1[r], mk);
            t2[r] += __shfl_xor(t2[r], mk);
        }
    }
    if (i == 0) {
#pragma unroll
        for (int r = 0; r < 4; ++r) {
            red[wv][0][G * 4 + r] = t1[r];
            red[wv][1][G * 4 + r] = t2[r];
        }
    }
    __syncthreads();
    f32x4 mu2, rs2;
#pragma unroll
    for (int r = 0; r < 4; ++r) {
        float T1 = red[0][0][G * 4 + r] + red[1][0][G * 4 + r];
        float T2 = red[0][1][G * 4 + r] + red[1][1][G * 4 + r];
        mu2[r] = T1 * (1.f / 256.f);
        float var = T2 * (1.f / 256.f) - mu2[r] * mu2[r];
        rs2[r] = rsqrtf(var + 1e-5f);
    }
#pragma unroll
    for (int nf8 = 0; nf8 < 8; ++nf8) {
        int col = (wv * 8 + nf8) * 16 + i;
        float gv = g1[col], bv = be1[col];
#pragma unroll
        for (int r = 0; r < 4; ++r) {
            out[(size_t)(m0 + G * 4 + r) * 256 + col] = (acc[nf8][r] - mu2[r]) * rs2[r] * gv + bv;
        }
    }
}

extern "C" void kernel_launch(void* const* d_in, const int* in_sizes, int n_in,
                              void* d_out, int out_size, void* d_ws, size_t ws_size,
                              hipStream_t stream) {
    const float* Q   = (const float*)d_in[0];
    const float* K   = (const float*)d_in[1];
    const float* Wq  = (const float*)d_in[2];
    const float* bq  = (const float*)d_in[3];
    const float* Wk  = (const float*)d_in[4];
    const float* bk  = (const float*)d_in[5];
    const float* Wv  = (const float*)d_in[6];
    const float* bv  = (const float*)d_in[7];
    const float* Wo  = (const float*)d_in[8];
    const float* bo  = (const float*)d_in[9];
    const float* g0  = (const float*)d_in[10];
    const float* be0 = (const float*)d_in[11];
    const float* g1  = (const float*)d_in[12];
    const float* be1 = (const float*)d_in[13];
    float* out = (float*)d_out;

    char* ws = (char*)d_ws;
    unsigned short* Wqf = (unsigned short*)(ws + (size_t)0);
    unsigned short* Wkf = (unsigned short*)(ws + ((size_t)128 << 10));
    unsigned short* Wvf = (unsigned short*)(ws + ((size_t)256 << 10));
    unsigned short* Wof = (unsigned short*)(ws + ((size_t)384 << 10));
    size_t off = (size_t)512 << 10;
    const size_t big = (size_t)8192 * 256 * 2;  // 4 MB each
    unsigned short* Kfp = (unsigned short*)(ws + off); off += big;
    unsigned short* Qp = (unsigned short*)(ws + off); off += big;
    unsigned short* Kf = (unsigned short*)(ws + off); off += big;
    unsigned short* Vf = (unsigned short*)(ws + off); off += big;
    unsigned short* Oa = (unsigned short*)(ws + off); off += big;  // unused (layout kept)
    unsigned short* Ob = (unsigned short*)(ws + off); off += 2 * big;  // split partials
    float* Lb = (float*)(ws + off); off += (size_t)2 * 16 * 4096 * 4;
    (void)Oa;

    k_cvt_all<<<2304, 256, 0, stream>>>(K, Wq, Wk, Wv, Wo,
                                        Kfp, Wqf, Wkf, Wvf, Wof);

    const float qscale = 1.4426950408889634f / sqrtf(32.0f);
    k_proj<<<1536, 128, 0, stream>>>(Q, Kfp, Wqf, Wkf, Wvf, bq, bk, bv,
                                     Qp, Kf, Vf, qscale);

    k_attn<<<1024, 256, 0, stream>>>(Qp, Kf, Vf, Ob, Lb);

    k_epi<<<512, 128, 0, stream>>>(Ob, Lb, Wof, bo, g0, be0, g1, be1, out);
}